// Round 7
// baseline (1308.823 us; speedup 1.0000x reference)
//
#include <hip/hip_runtime.h>
#include <hip/hip_bf16.h>

#define N_NODES 100000
#define N_EDGES 300000
#define IN_DIM 10
#define HID 384
#define OUT_DIM 3
#define T_LAYERS 5
#define BN_EPS 1e-5f

typedef __attribute__((ext_vector_type(8))) short short8;
typedef __attribute__((ext_vector_type(4))) float floatx4;

__device__ __forceinline__ float bf16f(short v) {
  return __uint_as_float(((unsigned)(unsigned short)v) << 16);
}

// async global->LDS, 16 B per lane; dst is wave-uniform base, lane l lands at
// dst + l*16 (linear). Swizzle lives on the SOURCE address (m173 pattern).
__device__ __forceinline__ void gld_lds16(const void* g, void* l) {
  __builtin_amdgcn_global_load_lds(
      (const __attribute__((address_space(1))) void*)g,
      (__attribute__((address_space(3))) void*)l, 16, 0, 0);
}

// ------------------------- CSR build -------------------------

__global__ void count_k(const int* __restrict__ dst, int* __restrict__ cnt, int E) {
  int e = blockIdx.x * blockDim.x + threadIdx.x;
  if (e < E) atomicAdd(&cnt[dst[e]], 1);
}

__global__ void scan_partial_k(const int* __restrict__ cnt, int* __restrict__ bsum, int n) {
  int t = threadIdx.x;
  int i = blockIdx.x * 1024 + t;
  int v = (i < n) ? cnt[i] : 0;
  #pragma unroll
  for (int off = 1; off < 64; off <<= 1) v += __shfl_xor(v, off);
  __shared__ int ws[16];
  if ((t & 63) == 0) ws[t >> 6] = v;
  __syncthreads();
  if (t == 0) {
    int s = 0;
    #pragma unroll
    for (int w = 0; w < 16; ++w) s += ws[w];
    bsum[blockIdx.x] = s;
  }
}

__global__ void scan_small_k(int* __restrict__ bsum, int P) {
  __shared__ int s[1024];
  int t = threadIdx.x;
  int v = (t < P) ? bsum[t] : 0;
  s[t] = v;
  __syncthreads();
  for (int off = 1; off < 1024; off <<= 1) {
    int add = (t >= off) ? s[t - off] : 0;
    __syncthreads();
    s[t] += add;
    __syncthreads();
  }
  if (t < P) bsum[t] = s[t] - v;  // exclusive block-prefix
}

__global__ void scan_final_k(const int* __restrict__ cnt, const int* __restrict__ bsum,
                             int* __restrict__ row_off, int n) {
  int t = threadIdx.x, lane = t & 63, wv = t >> 6;
  int i = blockIdx.x * 1024 + t;
  int v = (i < n) ? cnt[i] : 0;
  int x = v;
  #pragma unroll
  for (int off = 1; off < 64; off <<= 1) {
    int y = __shfl_up(x, off);
    if (lane >= off) x += y;
  }
  __shared__ int ws[16];
  if (lane == 63) ws[wv] = x;
  __syncthreads();
  if (t == 0) {
    int a = 0;
    #pragma unroll
    for (int w = 0; w < 16; ++w) { int tmp = ws[w]; ws[w] = a; a += tmp; }
  }
  __syncthreads();
  int excl = (x - v) + ws[wv] + bsum[blockIdx.x];
  if (i <= n) row_off[i] = excl;
}

__global__ void fill_k(const int* __restrict__ src, const int* __restrict__ dst,
                       const int* __restrict__ row_off, int* __restrict__ cursor,
                       int* __restrict__ csr, int E) {
  int e = blockIdx.x * blockDim.x + threadIdx.x;
  if (e < E) {
    int d = dst[e];
    int pos = atomicAdd(&cursor[d], 1);
    csr[row_off[d] + pos] = src[e];
  }
}

// ------------------------- prepack kernels -------------------------

__global__ void conv_k(const float* __restrict__ src, __hip_bfloat16* __restrict__ dst, int n) {
  int i = blockIdx.x * blockDim.x + threadIdx.x;
  if (i < n) dst[i] = __float2bfloat16(src[i]);
}

// X2[n][64] = { x[n][0..10) , agg10[n][0..10) , 0 pad }
__global__ void pack0_k(const float* __restrict__ x, const float* __restrict__ agg10,
                        __hip_bfloat16* __restrict__ X2, int n) {
  int i = blockIdx.x * blockDim.x + threadIdx.x;
  if (i < n * 64) {
    int node = i >> 6, k = i & 63;
    float v = (k < IN_DIM) ? x[node * IN_DIM + k]
              : (k < 2 * IN_DIM) ? agg10[node * IN_DIM + (k - IN_DIM)] : 0.f;
    X2[i] = __float2bfloat16(v);
  }
}

// W2[o][64] = { W_r0 (pairs x) , W_l0 (pairs agg10) , 0 pad }
__global__ void packw0_k(const float* __restrict__ Wl, const float* __restrict__ Wr,
                         __hip_bfloat16* __restrict__ W2) {
  int i = blockIdx.x * blockDim.x + threadIdx.x;
  if (i < HID * 64) {
    int o = i >> 6, k = i & 63;
    float v = (k < IN_DIM) ? Wr[o * IN_DIM + k]
              : (k < 2 * IN_DIM) ? Wl[o * IN_DIM + (k - IN_DIM)]
              : 0.f;
    W2[i] = __float2bfloat16(v);
  }
}

// ------------------------- layer-0 aggregation (10-dim fp32) -------------------------

__global__ void agg10_k(const float* __restrict__ x, const int* __restrict__ row_off,
                        const int* __restrict__ csr, float* __restrict__ agg10, int n) {
  int sub = threadIdx.x >> 5;
  int lane = threadIdx.x & 31;
  int node = blockIdx.x * 8 + sub;
  if (node >= n) return;
  int s = row_off[node], e = row_off[node + 1];
  if (lane < IN_DIM) {
    float acc = 0.f;
    for (int j = s; j < e; ++j) acc += x[csr[j] * IN_DIM + lane];
    float c = (float)max(e - s, 1);
    agg10[node * IN_DIM + lane] = acc / c;
  }
}

// ------------------------- MFMA GEMM, fused epilogue (r12, verified) ----------
// Used for layer 0 and the projection MLP. See r12 notes: 512 thr, gld_lds
// staging, counted-vmcnt A prefetch, raw barriers, 2 blocks/CU.
template <int KTOT, bool DUAL, int EPI, bool FINAL>
__global__ __launch_bounds__(512, 4) void mfma_gemm_k(
    const __hip_bfloat16* __restrict__ A1, const __hip_bfloat16* __restrict__ B1,
    const __hip_bfloat16* __restrict__ A2, const __hip_bfloat16* __restrict__ B2,
    const float* __restrict__ bias,
    const float* __restrict__ bng, const float* __restrict__ bnb,
    const float* __restrict__ bnm, const float* __restrict__ bnv,
    __hip_bfloat16* __restrict__ out,
    const float* __restrict__ W3, const float* __restrict__ b3,
    float* __restrict__ out3) {
  __shared__ alignas(16) short smem[32768];  // 65536 B
  short* sB = smem + 8192;

  const int t = threadIdx.x;
  const int lane = t & 63;
  const int wv = t >> 6;
  const int n16 = lane & 15;
  const int quad = lane >> 4;
  const int row0 = blockIdx.x * 64;

  const int aRow = t >> 3;
  const int aG = (t & 7) ^ (aRow & 7);
  const int aOff = min(row0 + aRow, N_NODES - 1) * KTOT + aG * 8;
  int bOff[6];
  #pragma unroll
  for (int it = 0; it < 6; ++it) {
    int col = (wv * 6 + it) * 8 + (lane >> 3);
    int g = (lane & 7) ^ (col & 7);
    bOff[it] = col * KTOT + g * 8;
  }

  floatx4 acc[4][3];
  #pragma unroll
  for (int rt = 0; rt < 4; ++rt)
    #pragma unroll
    for (int ct = 0; ct < 3; ++ct) acc[rt][ct] = (floatx4)0.f;

  constexpr int KCH = KTOT / 64;
  constexpr int NCH = DUAL ? 2 * KCH : KCH;

  gld_lds16(A1 + aOff, smem + wv * 512);

  for (int c = 0; c < NCH; ++c) {
    const __hip_bfloat16* Bp;
    int kc;
    if (!DUAL || c < KCH) { Bp = B1; kc = c * 64; }
    else                  { Bp = B2; kc = (c - KCH) * 64; }

    #pragma unroll
    for (int it = 0; it < 6; ++it)
      gld_lds16(Bp + bOff[it] + kc, sB + (wv * 6 + it) * 512);

    if (c + 1 < NCH) {
      const __hip_bfloat16* Ap;
      int kn;
      int cn = c + 1;
      if (!DUAL || cn < KCH) { Ap = A1; kn = cn * 64; }
      else                   { Ap = A2; kn = (cn - KCH) * 64; }
      gld_lds16(Ap + aOff + kn, smem + (cn & 1) * 4096 + wv * 512);
      asm volatile("s_waitcnt vmcnt(1)" ::: "memory");
    } else {
      asm volatile("s_waitcnt vmcnt(0)" ::: "memory");
    }
    __builtin_amdgcn_sched_barrier(0);
    __builtin_amdgcn_s_barrier();

    const short* sAc = smem + (c & 1) * 4096;
    #pragma unroll
    for (int kh = 0; kh < 2; ++kh) {
      short8 af[4];
      int g = kh * 4 + quad;
      #pragma unroll
      for (int rt = 0; rt < 4; ++rt) {
        int r = rt * 16 + n16;
        af[rt] = *(const short8*)&sAc[r * 64 + ((g ^ (r & 7)) * 8)];
      }
      #pragma unroll
      for (int ct = 0; ct < 3; ++ct) {
        int cl = wv * 48 + ct * 16 + n16;
        short8 bf = *(const short8*)&sB[cl * 64 + ((g ^ (cl & 7)) * 8)];
        #pragma unroll
        for (int rt = 0; rt < 4; ++rt)
          acc[rt][ct] = __builtin_amdgcn_mfma_f32_16x16x32_bf16(af[rt], bf, acc[rt][ct], 0, 0, 0);
      }
    }
    __builtin_amdgcn_s_barrier();
    asm volatile("" ::: "memory");
  }

  // ---- epilogue ----
  int gc[3];
  #pragma unroll
  for (int ct = 0; ct < 3; ++ct) {
    gc[ct] = wv * 48 + ct * 16 + n16;
    float bs = bias[gc[ct]];
    #pragma unroll
    for (int rt = 0; rt < 4; ++rt)
      #pragma unroll
      for (int rg = 0; rg < 4; ++rg) acc[rt][ct][rg] += bs;
  }

  if constexpr (EPI == 0) {
    float* red = (float*)smem;
    #pragma unroll
    for (int rt = 0; rt < 4; ++rt)
      #pragma unroll
      for (int rg = 0; rg < 4; ++rg) {
        float s = 0.f;
        #pragma unroll
        for (int ct = 0; ct < 3; ++ct) s += acc[rt][ct][rg] * acc[rt][ct][rg];
        #pragma unroll
        for (int off = 1; off < 16; off <<= 1) s += __shfl_xor(s, off);
        if (n16 == 0) red[wv * 64 + rt * 16 + quad * 4 + rg] = s;
      }
    __syncthreads();
    #pragma unroll
    for (int rt = 0; rt < 4; ++rt) {
      float inv[4];
      #pragma unroll
      for (int rg = 0; rg < 4; ++rg) {
        int rl = rt * 16 + quad * 4 + rg;
        float ss = 0.f;
        #pragma unroll
        for (int w = 0; w < 8; ++w) ss += red[w * 64 + rl];
        inv[rg] = 1.f / fmaxf(sqrtf(ss), 1e-12f);
      }
      #pragma unroll
      for (int ct = 0; ct < 3; ++ct)
        #pragma unroll
        for (int rg = 0; rg < 4; ++rg) acc[rt][ct][rg] *= inv[rg];
    }
    __syncthreads();
  }

  constexpr int OS = 392;
  short* sO = smem;
  #pragma unroll
  for (int ct = 0; ct < 3; ++ct) {
    int col = gc[ct];
    float sc = bng[col] * rsqrtf(bnv[col] + BN_EPS);
    float sh = bnb[col] - bnm[col] * sc;
    #pragma unroll
    for (int rt = 0; rt < 4; ++rt)
      #pragma unroll
      for (int rg = 0; rg < 4; ++rg) {
        float xv = acc[rt][ct][rg] * sc + sh;
        if constexpr (EPI == 0)
          xv = xv > 0.f ? xv : expm1f(xv);
        else
          xv = fmaxf(xv, 0.f);
        __hip_bfloat16 bv = __float2bfloat16(xv);
        sO[(rt * 16 + quad * 4 + rg) * OS + col] = *(short*)&bv;
      }
  }
  __syncthreads();

  if constexpr (FINAL) {
    if (t < 192) {
      int row = t & 63, o = t >> 6;
      int grow = row0 + row;
      if (grow < N_NODES) {
        float s = 0.f;
        #pragma unroll
        for (int kb = 0; kb < 48; ++kb) {
          short8 hv = *(const short8*)&sO[row * OS + kb * 8];
          #pragma unroll
          for (int j = 0; j < 8; ++j) s += bf16f(hv[j]) * W3[o * HID + kb * 8 + j];
        }
        out3[grow * OUT_DIM + o] = s + b3[o];
      }
    }
  } else {
    #pragma unroll
    for (int it = 0; it < 6; ++it) {
      int e = t + it * 512;
      int row = e / 48, cs = e % 48;
      int grow = row0 + row;
      if (grow < N_NODES) {
        uint4 v = *(const uint4*)&sO[row * OS + cs * 8];
        *(uint4*)(out + (size_t)grow * HID + cs * 8) = v;
      }
    }
  }
}

// ------------------------- fused SAGE layer (r13) -------------------------
// hdst = ELU(BN(L2norm( aggT @ Wl^T + bias + h @ Wr^T )))  for 64 nodes/block.
// Gather phase: 16 waves x 4 nodes mean-aggregate neighbor rows of hsrc
// directly into LDS aggT[64][384] (bf16, granule-XOR swizzled like sA), then
// the r12 K-loop runs with chunks 0..5 streaming hsrc (gld_lds dbuf + counted
// vmcnt) and chunks 6..11 reading A-fragments straight from aggT (no staging,
// no stall). Removes aggv_k + the 153.6 MB/layer agg round-trip.
// NOT in-place (blocks read random neighbor rows): launcher ping-pongs h0/h1.
// 1024 thr = 16 waves, acc[2][3] = 24 regs/wave; LDS 48+48+16 = 112 KB ->
// 1 block/CU, 16 waves/CU (same as r12's 2x8).
__global__ __launch_bounds__(1024, 4) void fused_sage_k(
    const __hip_bfloat16* __restrict__ hsrc,
    const int* __restrict__ row_off, const int* __restrict__ csr,
    const __hip_bfloat16* __restrict__ Wl, const __hip_bfloat16* __restrict__ Wr,
    const float* __restrict__ bias,
    const float* __restrict__ bng, const float* __restrict__ bnb,
    const float* __restrict__ bnm, const float* __restrict__ bnv,
    __hip_bfloat16* __restrict__ hdst) {
  // shorts: [0,24576) aggT 64x384 | [24576,49152) sB 384x64 | [49152,57344) sA dbuf
  __shared__ alignas(16) short smem[57344];  // 114688 B
  short* aggT = smem;
  short* sB = smem + 24576;
  short* sA = smem + 49152;

  const int t = threadIdx.x;
  const int lane = t & 63;
  const int wv = t >> 6;          // 0..15
  const int n16 = lane & 15;
  const int quad = lane >> 4;
  const int row0 = blockIdx.x * 64;

  // prologue: prefetch h-chunk 0 (waves 0..7 stage rows wv*8..wv*8+7)
  int aOff = 0;
  if (wv < 8) {
    int r = wv * 8 + (lane >> 3);
    int g = (lane & 7) ^ (r & 7);
    aOff = min(row0 + r, N_NODES - 1) * HID + g * 8;
    gld_lds16(hsrc + aOff, sA + wv * 512);
  }

  // B staging offsets: 3 gld per wave, instr j = wv*3+it covers cols j*8..+7
  int bOff[3];
  #pragma unroll
  for (int it = 0; it < 3; ++it) {
    int col = (wv * 3 + it) * 8 + (lane >> 3);
    int g = (lane & 7) ^ (col & 7);
    bOff[it] = col * HID + g * 8;
  }

  // ---- gather phase: mean of neighbor rows -> aggT (swizzled bf16) ----
  if (lane < 48) {
    #pragma unroll 1
    for (int i = 0; i < 4; ++i) {
      int r = wv * 4 + i;
      int node = row0 + r;
      // write dest: chunk (lane>>3), granule slot (lane&7)^(r&7)
      int dcol = (lane >> 3) * 64 + (((lane & 7) ^ (r & 7)) * 8);
      uint o0 = 0, o1 = 0, o2 = 0, o3 = 0;
      if (node < N_NODES) {
        int s = row_off[node], e = row_off[node + 1];
        float a0 = 0, a1 = 0, a2 = 0, a3 = 0, a4 = 0, a5 = 0, a6 = 0, a7 = 0;
        for (int j = s; j < e; ++j) {
          const uint4 v = *(const uint4*)(hsrc + (size_t)csr[j] * HID + lane * 8);
          a0 += __uint_as_float(v.x << 16); a1 += __uint_as_float(v.x & 0xffff0000u);
          a2 += __uint_as_float(v.y << 16); a3 += __uint_as_float(v.y & 0xffff0000u);
          a4 += __uint_as_float(v.z << 16); a5 += __uint_as_float(v.z & 0xffff0000u);
          a6 += __uint_as_float(v.w << 16); a7 += __uint_as_float(v.w & 0xffff0000u);
        }
        float invc = 1.f / (float)max(e - s, 1);
        __hip_bfloat16 b0 = __float2bfloat16(a0 * invc), b1 = __float2bfloat16(a1 * invc);
        __hip_bfloat16 b2 = __float2bfloat16(a2 * invc), b3 = __float2bfloat16(a3 * invc);
        __hip_bfloat16 b4 = __float2bfloat16(a4 * invc), b5 = __float2bfloat16(a5 * invc);
        __hip_bfloat16 b6 = __float2bfloat16(a6 * invc), b7 = __float2bfloat16(a7 * invc);
        o0 = (uint)(*(unsigned short*)&b0) | ((uint)(*(unsigned short*)&b1) << 16);
        o1 = (uint)(*(unsigned short*)&b2) | ((uint)(*(unsigned short*)&b3) << 16);
        o2 = (uint)(*(unsigned short*)&b4) | ((uint)(*(unsigned short*)&b5) << 16);
        o3 = (uint)(*(unsigned short*)&b6) | ((uint)(*(unsigned short*)&b7) << 16);
      }
      *(uint4*)&aggT[r * HID + dcol] = make_uint4(o0, o1, o2, o3);
    }
  }
  __syncthreads();  // aggT complete (also drains the prologue prefetch - fine)

  const int wr = wv >> 3, wc = wv & 7;  // 2 row-halves x 8 col-slices
  floatx4 acc[2][3];
  #pragma unroll
  for (int rt = 0; rt < 2; ++rt)
    #pragma unroll
    for (int ct = 0; ct < 3; ++ct) acc[rt][ct] = (floatx4)0.f;

  // ---- K-loop: chunks 0..5 stream hsrc x Wr; 6..11 read aggT x Wl ----
  #pragma unroll
  for (int c = 0; c < 12; ++c) {
    const __hip_bfloat16* Bp = (c < 6) ? Wr : Wl;
    const int kc = (c < 6 ? c : c - 6) * 64;

    #pragma unroll
    for (int it = 0; it < 3; ++it)
      gld_lds16(Bp + bOff[it] + kc, sB + (wv * 3 + it) * 512);

    const bool pf = (wv < 8) && (c + 1 < 6);
    if (pf) {
      gld_lds16(hsrc + aOff + (c + 1) * 64, sA + ((c + 1) & 1) * 4096 + wv * 512);
      asm volatile("s_waitcnt vmcnt(1)" ::: "memory");
    } else {
      asm volatile("s_waitcnt vmcnt(0)" ::: "memory");
    }
    __builtin_amdgcn_sched_barrier(0);
    __builtin_amdgcn_s_barrier();

    #pragma unroll
    for (int kh = 0; kh < 2; ++kh) {
      short8 af[2];
      int g = kh * 4 + quad;
      #pragma unroll
      for (int rt = 0; rt < 2; ++rt) {
        int r = wr * 32 + rt * 16 + n16;
        if (c < 6)
          af[rt] = *(const short8*)&sA[(c & 1) * 4096 + r * 64 + ((g ^ (r & 7)) * 8)];
        else
          af[rt] = *(const short8*)&aggT[r * HID + kc + ((g ^ (r & 7)) * 8)];
      }
      #pragma unroll
      for (int ct = 0; ct < 3; ++ct) {
        int cl = wc * 48 + ct * 16 + n16;
        short8 bf = *(const short8*)&sB[cl * 64 + ((g ^ (cl & 7)) * 8)];
        #pragma unroll
        for (int rt = 0; rt < 2; ++rt)
          acc[rt][ct] = __builtin_amdgcn_mfma_f32_16x16x32_bf16(af[rt], bf, acc[rt][ct], 0, 0, 0);
      }
    }
    __builtin_amdgcn_s_barrier();
    asm volatile("" ::: "memory");
  }

  // ---- epilogue: bias -> L2 norm -> BN -> ELU -> pack -> coalesced out ----
  int gc[3];
  #pragma unroll
  for (int ct = 0; ct < 3; ++ct) {
    gc[ct] = wc * 48 + ct * 16 + n16;
    float bs = bias[gc[ct]];
    #pragma unroll
    for (int rt = 0; rt < 2; ++rt)
      #pragma unroll
      for (int rg = 0; rg < 4; ++rg) acc[rt][ct][rg] += bs;
  }

  float* red = (float*)sA;  // 512 floats, sA region is free now
  #pragma unroll
  for (int rt = 0; rt < 2; ++rt)
    #pragma unroll
    for (int rg = 0; rg < 4; ++rg) {
      float s = 0.f;
      #pragma unroll
      for (int ct = 0; ct < 3; ++ct) s += acc[rt][ct][rg] * acc[rt][ct][rg];
      #pragma unroll
      for (int off = 1; off < 16; off <<= 1) s += __shfl_xor(s, off);
      if (n16 == 0) red[wv * 32 + rt * 16 + quad * 4 + rg] = s;
    }
  __syncthreads();
  #pragma unroll
  for (int rt = 0; rt < 2; ++rt) {
    float inv[4];
    #pragma unroll
    for (int rg = 0; rg < 4; ++rg) {
      int lr = rt * 16 + quad * 4 + rg;
      float ss = 0.f;
      #pragma unroll
      for (int w8 = 0; w8 < 8; ++w8) ss += red[(wr * 8 + w8) * 32 + lr];
      inv[rg] = 1.f / fmaxf(sqrtf(ss), 1e-12f);
    }
    #pragma unroll
    for (int ct = 0; ct < 3; ++ct)
      #pragma unroll
      for (int rg = 0; rg < 4; ++rg) acc[rt][ct][rg] *= inv[rg];
  }
  __syncthreads();  // red reads done; aggT/sB regions now reusable as sO

  constexpr int OS = 392;
  short* sO = smem;  // 64 * 392 shorts = 50176 B
  #pragma unroll
  for (int ct = 0; ct < 3; ++ct) {
    int col = gc[ct];
    float sc = bng[col] * rsqrtf(bnv[col] + BN_EPS);
    float sh = bnb[col] - bnm[col] * sc;
    #pragma unroll
    for (int rt = 0; rt < 2; ++rt)
      #pragma unroll
      for (int rg = 0; rg < 4; ++rg) {
        float xv = acc[rt][ct][rg] * sc + sh;
        xv = xv > 0.f ? xv : expm1f(xv);
        __hip_bfloat16 bv = __float2bfloat16(xv);
        sO[(wr * 32 + rt * 16 + quad * 4 + rg) * OS + col] = *(short*)&bv;
      }
  }
  __syncthreads();

  // 64 rows x 768 B out; 48 16B-chunks per row; 1024 thr x 3 chunks
  #pragma unroll
  for (int it = 0; it < 3; ++it) {
    int e = t + it * 1024;
    int row = e / 48, cs = e % 48;
    int grow = row0 + row;
    if (grow < N_NODES) {
      uint4 v = *(const uint4*)&sO[row * OS + cs * 8];
      *(uint4*)(hdst + (size_t)grow * HID + cs * 8) = v;
    }
  }
}

// ------------------------- launcher -------------------------

extern "C" void kernel_launch(void* const* d_in, const int* in_sizes, int n_in,
                              void* d_out, int out_size, void* d_ws, size_t ws_size,
                              hipStream_t stream) {
  const float* x = (const float*)d_in[0];
  const int* ei = (const int*)d_in[1];
  const int* src = ei;
  const int* dst = ei + N_EDGES;
  const float* W_l0 = (const float*)d_in[2];
  const float* b_l0 = (const float*)d_in[3];
  const float* W_r0 = (const float*)d_in[4];
  const float* W_l = (const float*)d_in[5];
  const float* b_l = (const float*)d_in[6];
  const float* W_r = (const float*)d_in[7];
  const float* bn_g = (const float*)d_in[8];
  const float* bn_b = (const float*)d_in[9];
  const float* bn_m = (const float*)d_in[10];
  const float* bn_v = (const float*)d_in[11];
  const float* Wp0 = (const float*)d_in[12];
  const float* bp0 = (const float*)d_in[13];
  const float* Wp1 = (const float*)d_in[14];
  const float* bp1 = (const float*)d_in[15];
  const float* Wp2 = (const float*)d_in[16];
  const float* bp2 = (const float*)d_in[17];
  const float* pbn_g = (const float*)d_in[18];
  const float* pbn_b = (const float*)d_in[19];
  const float* pbn_m = (const float*)d_in[20];
  const float* pbn_v = (const float*)d_in[21];

  char* ws = (char*)d_ws;
  size_t off = 0;
  auto walloc = [&](size_t bytes) -> void* {
    void* p = ws + off;
    off = (off + bytes + 255) & ~(size_t)255;
    return p;
  };
  __hip_bfloat16* h0  = (__hip_bfloat16*)walloc((size_t)N_NODES * HID * 2);  // 76.8 MB
  __hip_bfloat16* h1  = (__hip_bfloat16*)walloc((size_t)N_NODES * HID * 2);  // 76.8 MB
  float* agg10 = (float*)h1;  // 4 MB fp32 overlay; h1 not used until layer 1
  __hip_bfloat16* X2  = (__hip_bfloat16*)walloc((size_t)N_NODES * 64 * 2);   // 12.8 MB
  __hip_bfloat16* W2  = (__hip_bfloat16*)walloc((size_t)HID * 64 * 2);
  __hip_bfloat16* WlB  = (__hip_bfloat16*)walloc((size_t)(T_LAYERS - 1) * HID * HID * 2);
  __hip_bfloat16* WrB  = (__hip_bfloat16*)walloc((size_t)(T_LAYERS - 1) * HID * HID * 2);
  __hip_bfloat16* Wp0B = (__hip_bfloat16*)walloc((size_t)HID * HID * 2);
  __hip_bfloat16* Wp1B = (__hip_bfloat16*)walloc((size_t)HID * HID * 2);
  int* cnt     = (int*)walloc((size_t)N_NODES * 4);
  int* row_off = (int*)walloc((size_t)(N_NODES + 1) * 4);
  int* cursor  = (int*)walloc((size_t)N_NODES * 4);
  int* csr     = (int*)walloc((size_t)N_EDGES * 4);
  int* bsum    = (int*)walloc(4096);

  hipMemsetAsync(cnt, 0, (size_t)N_NODES * 4, stream);
  hipMemsetAsync(cursor, 0, (size_t)N_NODES * 4, stream);

  // weight prepack
  const int NW = (T_LAYERS - 1) * HID * HID;
  conv_k<<<(NW + 255) / 256, 256, 0, stream>>>(W_l, WlB, NW);
  conv_k<<<(NW + 255) / 256, 256, 0, stream>>>(W_r, WrB, NW);
  conv_k<<<(HID * HID + 255) / 256, 256, 0, stream>>>(Wp0, Wp0B, HID * HID);
  conv_k<<<(HID * HID + 255) / 256, 256, 0, stream>>>(Wp1, Wp1B, HID * HID);
  packw0_k<<<(HID * 64 + 255) / 256, 256, 0, stream>>>(W_l0, W_r0, W2);

  // CSR build
  count_k<<<(N_EDGES + 255) / 256, 256, 0, stream>>>(dst, cnt, N_EDGES);
  int P = (N_NODES + 1 + 1023) / 1024;
  scan_partial_k<<<P, 1024, 0, stream>>>(cnt, bsum, N_NODES);
  scan_small_k<<<1, 1024, 0, stream>>>(bsum, P);
  scan_final_k<<<P, 1024, 0, stream>>>(cnt, bsum, row_off, N_NODES);
  fill_k<<<(N_EDGES + 255) / 256, 256, 0, stream>>>(src, dst, row_off, cursor, csr, N_EDGES);

  const int GB = (N_NODES + 63) / 64;  // 1563 row-blocks

  // layer 0: agg10 -> pack -> MFMA GEMM (K=64: [x|agg10|pad] x [Wr0|Wl0|pad])
  agg10_k<<<(N_NODES + 7) / 8, 256, 0, stream>>>(x, row_off, csr, agg10, N_NODES);
  pack0_k<<<(N_NODES * 64 + 255) / 256, 256, 0, stream>>>(x, agg10, X2, N_NODES);
  mfma_gemm_k<64, false, 0, false><<<GB, 512, 0, stream>>>(
      X2, W2, nullptr, nullptr, b_l0, bn_g, bn_b, bn_m, bn_v, h0,
      nullptr, nullptr, nullptr);

  // layers 1..4: fused gather + dual GEMM, ping-pong h0 <-> h1
  __hip_bfloat16* hin = h0;
  __hip_bfloat16* hout = h1;
  for (int t = 1; t < T_LAYERS; ++t) {
    fused_sage_k<<<GB, 1024, 0, stream>>>(
        hin, row_off, csr,
        WlB + (size_t)(t - 1) * HID * HID,
        WrB + (size_t)(t - 1) * HID * HID,
        b_l + (size_t)(t - 1) * HID,
        bn_g + (size_t)t * HID, bn_b + (size_t)t * HID,
        bn_m + (size_t)t * HID, bn_v + (size_t)t * HID,
        hout);
    __hip_bfloat16* tmp = hin; hin = hout; hout = tmp;
  }
  // after 4 layers result is in hin (== h0)

  // projection MLP: proj0 in-place on hin; proj1 fused with the 384->3 output
  mfma_gemm_k<HID, false, 1, false><<<GB, 512, 0, stream>>>(
      hin, Wp0B, nullptr, nullptr, bp0, pbn_g, pbn_b, pbn_m, pbn_v, hin,
      nullptr, nullptr, nullptr);
  mfma_gemm_k<HID, false, 1, true><<<GB, 512, 0, stream>>>(
      hin, Wp1B, nullptr, nullptr, bp1, pbn_g + HID, pbn_b + HID, pbn_m + HID, pbn_v + HID, hin,
      Wp2, bp2, (float*)d_out);
}

// Round 8
// 1129.913 us; speedup vs baseline: 1.1583x; 1.1583x over previous
//
#include <hip/hip_runtime.h>
#include <hip/hip_bf16.h>

#define N_NODES 100000
#define N_EDGES 300000
#define IN_DIM 10
#define HID 384
#define OUT_DIM 3
#define T_LAYERS 5
#define BN_EPS 1e-5f

typedef __attribute__((ext_vector_type(8))) short short8;
typedef __attribute__((ext_vector_type(4))) float floatx4;

__device__ __forceinline__ float bf16f(short v) {
  return __uint_as_float(((unsigned)(unsigned short)v) << 16);
}

// async global->LDS, 16 B per lane; dst is wave-uniform base, lane l lands at
// dst + l*16 (linear). Swizzle lives on the SOURCE address (m173 pattern).
__device__ __forceinline__ void gld_lds16(const void* g, void* l) {
  __builtin_amdgcn_global_load_lds(
      (const __attribute__((address_space(1))) void*)g,
      (__attribute__((address_space(3))) void*)l, 16, 0, 0);
}

// ------------------------- CSR build -------------------------

__global__ void count_k(const int* __restrict__ dst, int* __restrict__ cnt, int E) {
  int e = blockIdx.x * blockDim.x + threadIdx.x;
  if (e < E) atomicAdd(&cnt[dst[e]], 1);
}

__global__ void scan_partial_k(const int* __restrict__ cnt, int* __restrict__ bsum, int n) {
  int t = threadIdx.x;
  int i = blockIdx.x * 1024 + t;
  int v = (i < n) ? cnt[i] : 0;
  #pragma unroll
  for (int off = 1; off < 64; off <<= 1) v += __shfl_xor(v, off);
  __shared__ int ws[16];
  if ((t & 63) == 0) ws[t >> 6] = v;
  __syncthreads();
  if (t == 0) {
    int s = 0;
    #pragma unroll
    for (int w = 0; w < 16; ++w) s += ws[w];
    bsum[blockIdx.x] = s;
  }
}

__global__ void scan_small_k(int* __restrict__ bsum, int P) {
  __shared__ int s[1024];
  int t = threadIdx.x;
  int v = (t < P) ? bsum[t] : 0;
  s[t] = v;
  __syncthreads();
  for (int off = 1; off < 1024; off <<= 1) {
    int add = (t >= off) ? s[t - off] : 0;
    __syncthreads();
    s[t] += add;
    __syncthreads();
  }
  if (t < P) bsum[t] = s[t] - v;  // exclusive block-prefix
}

__global__ void scan_final_k(const int* __restrict__ cnt, const int* __restrict__ bsum,
                             int* __restrict__ row_off, int n) {
  int t = threadIdx.x, lane = t & 63, wv = t >> 6;
  int i = blockIdx.x * 1024 + t;
  int v = (i < n) ? cnt[i] : 0;
  int x = v;
  #pragma unroll
  for (int off = 1; off < 64; off <<= 1) {
    int y = __shfl_up(x, off);
    if (lane >= off) x += y;
  }
  __shared__ int ws[16];
  if (lane == 63) ws[wv] = x;
  __syncthreads();
  if (t == 0) {
    int a = 0;
    #pragma unroll
    for (int w = 0; w < 16; ++w) { int tmp = ws[w]; ws[w] = a; a += tmp; }
  }
  __syncthreads();
  int excl = (x - v) + ws[wv] + bsum[blockIdx.x];
  if (i <= n) row_off[i] = excl;
}

__global__ void fill_k(const int* __restrict__ src, const int* __restrict__ dst,
                       const int* __restrict__ row_off, int* __restrict__ cursor,
                       int* __restrict__ csr, int E) {
  int e = blockIdx.x * blockDim.x + threadIdx.x;
  if (e < E) {
    int d = dst[e];
    int pos = atomicAdd(&cursor[d], 1);
    csr[row_off[d] + pos] = src[e];
  }
}

// ------------------------- prepack kernels -------------------------

__global__ void conv_k(const float* __restrict__ src, __hip_bfloat16* __restrict__ dst, int n) {
  int i = blockIdx.x * blockDim.x + threadIdx.x;
  if (i < n) dst[i] = __float2bfloat16(src[i]);
}

// X2[n][64] = { x[n][0..10) , agg10[n][0..10) , 0 pad }
__global__ void pack0_k(const float* __restrict__ x, const float* __restrict__ agg10,
                        __hip_bfloat16* __restrict__ X2, int n) {
  int i = blockIdx.x * blockDim.x + threadIdx.x;
  if (i < n * 64) {
    int node = i >> 6, k = i & 63;
    float v = (k < IN_DIM) ? x[node * IN_DIM + k]
              : (k < 2 * IN_DIM) ? agg10[node * IN_DIM + (k - IN_DIM)] : 0.f;
    X2[i] = __float2bfloat16(v);
  }
}

// W2[o][64] = { W_r0 (pairs x) , W_l0 (pairs agg10) , 0 pad }
__global__ void packw0_k(const float* __restrict__ Wl, const float* __restrict__ Wr,
                         __hip_bfloat16* __restrict__ W2) {
  int i = blockIdx.x * blockDim.x + threadIdx.x;
  if (i < HID * 64) {
    int o = i >> 6, k = i & 63;
    float v = (k < IN_DIM) ? Wr[o * IN_DIM + k]
              : (k < 2 * IN_DIM) ? Wl[o * IN_DIM + (k - IN_DIM)]
              : 0.f;
    W2[i] = __float2bfloat16(v);
  }
}

// ------------------------- aggregation -------------------------

__global__ void agg10_k(const float* __restrict__ x, const int* __restrict__ row_off,
                        const int* __restrict__ csr, float* __restrict__ agg10, int n) {
  int sub = threadIdx.x >> 5;
  int lane = threadIdx.x & 31;
  int node = blockIdx.x * 8 + sub;
  if (node >= n) return;
  int s = row_off[node], e = row_off[node + 1];
  if (lane < IN_DIM) {
    float acc = 0.f;
    for (int j = s; j < e; ++j) acc += x[csr[j] * IN_DIM + lane];
    float c = (float)max(e - s, 1);
    agg10[node * IN_DIM + lane] = acc / c;
  }
}

// F=384 mean aggregation: one wave per node, lanes 0..47 hold 8 bf16 cols each.
// Kept as a SEPARATE kernel (r13 post-mortem: fusing the gather into the GEMM
// traps it behind a block barrier at 16 waves/CU; standalone it gets ~32
// waves/CU of latency hiding and ran ~55us — fusion cost +40us/layer).
__global__ __launch_bounds__(256) void aggv_k(const __hip_bfloat16* __restrict__ h,
                                              const int* __restrict__ row_off,
                                              const int* __restrict__ csr,
                                              __hip_bfloat16* __restrict__ agg, int n) {
  int node = blockIdx.x * 4 + (threadIdx.x >> 6);
  if (node >= n) return;
  int lane = threadIdx.x & 63;
  if (lane >= 48) return;
  int s = row_off[node], e = row_off[node + 1];
  float acc[8] = {0.f, 0.f, 0.f, 0.f, 0.f, 0.f, 0.f, 0.f};
  for (int j = s; j < e; ++j) {
    const uint4 v = *(const uint4*)(h + (size_t)csr[j] * HID + lane * 8);
    uint u0 = v.x, u1 = v.y, u2 = v.z, u3 = v.w;
    acc[0] += __uint_as_float(u0 << 16);
    acc[1] += __uint_as_float(u0 & 0xffff0000u);
    acc[2] += __uint_as_float(u1 << 16);
    acc[3] += __uint_as_float(u1 & 0xffff0000u);
    acc[4] += __uint_as_float(u2 << 16);
    acc[5] += __uint_as_float(u2 & 0xffff0000u);
    acc[6] += __uint_as_float(u3 << 16);
    acc[7] += __uint_as_float(u3 & 0xffff0000u);
  }
  float invc = 1.f / (float)max(e - s, 1);
  uint out[4];
  #pragma unroll
  for (int q = 0; q < 4; ++q) {
    __hip_bfloat16 lo = __float2bfloat16(acc[2 * q] * invc);
    __hip_bfloat16 hi = __float2bfloat16(acc[2 * q + 1] * invc);
    out[q] = (uint)(*(unsigned short*)&lo) | ((uint)(*(unsigned short*)&hi) << 16);
  }
  *(uint4*)(agg + (size_t)node * HID + lane * 8) = make_uint4(out[0], out[1], out[2], out[3]);
}

// ------------------------- MFMA GEMM, fused epilogue -------------------------
// out[i, col] = sum_k A1[i,k]*B1[col,k] (+ A2[i,k]*B2[col,k]) + bias[col]
// r14 = r12's compute core at BM=128 with BOTH operands double-buffered:
//  * r12 exposed B's L2 latency every chunk (B staged distance-0, vmcnt(1)
//    waits for it right before the barrier). Full chunk-ahead needs LDS for
//    2x(A+B); impossible at BM=64 / 2 blocks/CU, but >64KB static LDS works
//    (r13 ran 114KB). BM=128, 1024 thr, 16 waves, LDS = A-dbuf 32KB +
//    B-dbuf 96KB = 128KB, 1 block/CU -> same 16 waves/CU as r12.
//  * Per chunk each wave issues exactly 4 gld_lds (3 B + 1 A) for chunk c+1,
//    then vmcnt(4): waits only the 4 older chunk-c loads, chunk-c+1 stays in
//    flight across the barrier -> zero exposed load latency steady-state.
//  * B staged once per 128 rows (was twice): LDS-write traffic/row -43%.
//  * Per-wave geometry identical to r12: 64x48 tile, acc[4][3], 14 ds_read
//    per chunk, same XOR granule swizzle on source addresses.
// Epilogue: pack bf16 to LDS sO[128][392], coalesced dwordx4 out.
// In-place safe (out == A1 or A2): block reads only its own 128 rows.
template <int KTOT, bool DUAL, int EPI, bool FINAL>
__global__ __launch_bounds__(1024, 4) void mfma_gemm_k(
    const __hip_bfloat16* __restrict__ A1, const __hip_bfloat16* __restrict__ B1,
    const __hip_bfloat16* __restrict__ A2, const __hip_bfloat16* __restrict__ B2,
    const float* __restrict__ bias,
    const float* __restrict__ bng, const float* __restrict__ bnb,
    const float* __restrict__ bnm, const float* __restrict__ bnv,
    __hip_bfloat16* __restrict__ out,
    const float* __restrict__ W3, const float* __restrict__ b3,
    float* __restrict__ out3) {
  // shorts: [0,8192) sA par0 | [8192,16384) sA par1
  //         [16384,40960) sB par0 | [40960,65536) sB par1      = 128 KB
  // epilogue reuses [0,50176) as sO[128][392]; [0,1024) floats as red
  __shared__ alignas(16) short smem[65536];

  const int t = threadIdx.x;
  const int lane = t & 63;
  const int wv = t >> 6;        // 0..15
  const int n16 = lane & 15;
  const int quad = lane >> 4;
  const int row0 = blockIdx.x * 128;

  // ---- staging geometry (per-thread constant source offsets) ----
  // A: 1 gld_lds per wave; instr wv covers rows wv*8..wv*8+7 (128 rows).
  const int aRow = t >> 3;                  // 0..127
  const int aG = (t & 7) ^ (aRow & 7);
  const int aOff = min(row0 + aRow, N_NODES - 1) * KTOT + aG * 8;  // elements
  // B: 3 gld_lds per wave; instr j = wv*3+it covers cols j*8..j*8+7 (384).
  int bOff[3];
  #pragma unroll
  for (int it = 0; it < 3; ++it) {
    int col = (wv * 3 + it) * 8 + (lane >> 3);
    int g = (lane & 7) ^ (col & 7);
    bOff[it] = col * KTOT + g * 8;  // elements
  }

  const int wr = wv >> 3, wc = wv & 7;  // 2 row-halves x 8 col-slices

  floatx4 acc[4][3];
  #pragma unroll
  for (int rt = 0; rt < 4; ++rt)
    #pragma unroll
    for (int ct = 0; ct < 3; ++ct) acc[rt][ct] = (floatx4)0.f;

  constexpr int KCH = KTOT / 64;
  constexpr int NCH = DUAL ? 2 * KCH : KCH;

  auto stage = [&](int c) {
    const __hip_bfloat16* Ap;
    const __hip_bfloat16* Bp;
    int kc;
    if (!DUAL || c < KCH) { Ap = A1; Bp = B1; kc = c * 64; }
    else                  { Ap = A2; Bp = B2; kc = (c - KCH) * 64; }
    short* sAb = smem + (c & 1) * 8192;
    short* sBb = smem + 16384 + (c & 1) * 24576;
    #pragma unroll
    for (int it = 0; it < 3; ++it)
      gld_lds16(Bp + bOff[it] + kc, sBb + (wv * 3 + it) * 512);
    gld_lds16(Ap + aOff + kc, sAb + wv * 512);
  };

  // prologue: stage chunk 0 into parity 0 (4 loads/wave in flight)
  stage(0);

  for (int c = 0; c < NCH; ++c) {
    // stage chunk c+1 into the other parity; it stays in flight across the
    // barrier. vmcnt(4) waits only the 4 older (chunk-c) loads of THIS wave;
    // combined with s_barrier, all of chunk c is visible to all waves.
    if (c + 1 < NCH) {
      stage(c + 1);
      asm volatile("s_waitcnt vmcnt(4)" ::: "memory");
    } else {
      asm volatile("s_waitcnt vmcnt(0)" ::: "memory");
    }
    __builtin_amdgcn_sched_barrier(0);
    __builtin_amdgcn_s_barrier();

    const short* sAc = smem + (c & 1) * 8192;
    const short* sBc = smem + 16384 + (c & 1) * 24576;
    #pragma unroll
    for (int kh = 0; kh < 2; ++kh) {
      short8 af[4];
      int g = kh * 4 + quad;
      #pragma unroll
      for (int rt = 0; rt < 4; ++rt) {
        int r = wr * 64 + rt * 16 + n16;
        af[rt] = *(const short8*)&sAc[r * 64 + ((g ^ (r & 7)) * 8)];
      }
      #pragma unroll
      for (int ct = 0; ct < 3; ++ct) {
        int cl = wc * 48 + ct * 16 + n16;
        short8 bf = *(const short8*)&sBc[cl * 64 + ((g ^ (cl & 7)) * 8)];
        #pragma unroll
        for (int rt = 0; rt < 4; ++rt)
          acc[rt][ct] = __builtin_amdgcn_mfma_f32_16x16x32_bf16(af[rt], bf, acc[rt][ct], 0, 0, 0);
      }
    }
    __builtin_amdgcn_s_barrier();   // all reads of parity c&1 done before re-stage
    asm volatile("" ::: "memory");
  }

  // ---- epilogue ----
  int gc[3];
  #pragma unroll
  for (int ct = 0; ct < 3; ++ct) {
    gc[ct] = wc * 48 + ct * 16 + n16;
    float bs = bias[gc[ct]];
    #pragma unroll
    for (int rt = 0; rt < 4; ++rt)
      #pragma unroll
      for (int rg = 0; rg < 4; ++rg) acc[rt][ct][rg] += bs;
  }

  if constexpr (EPI == 0) {
    // row L2 norm: 16-lane shfl partials (sums this wave's 48 cols), then
    // cross-wave (8 col-slices per row-half) via LDS red[16][64].
    float* red = (float*)smem;  // 1024 floats
    #pragma unroll
    for (int rt = 0; rt < 4; ++rt)
      #pragma unroll
      for (int rg = 0; rg < 4; ++rg) {
        float s = 0.f;
        #pragma unroll
        for (int ct = 0; ct < 3; ++ct) s += acc[rt][ct][rg] * acc[rt][ct][rg];
        #pragma unroll
        for (int off = 1; off < 16; off <<= 1) s += __shfl_xor(s, off);
        if (n16 == 0) red[wv * 64 + rt * 16 + quad * 4 + rg] = s;
      }
    __syncthreads();
    #pragma unroll
    for (int rt = 0; rt < 4; ++rt) {
      float inv[4];
      #pragma unroll
      for (int rg = 0; rg < 4; ++rg) {
        int lr = rt * 16 + quad * 4 + rg;
        float ss = 0.f;
        #pragma unroll
        for (int w8 = 0; w8 < 8; ++w8) ss += red[(wr * 8 + w8) * 64 + lr];
        inv[rg] = 1.f / fmaxf(sqrtf(ss), 1e-12f);
      }
      #pragma unroll
      for (int ct = 0; ct < 3; ++ct)
        #pragma unroll
        for (int rg = 0; rg < 4; ++rg) acc[rt][ct][rg] *= inv[rg];
    }
    __syncthreads();  // red reads done before smem reused as sO
  }

  // BN + activation, pack bf16 into LDS (row stride 392 shorts)
  constexpr int OS = 392;  // 128 * 392 * 2 B = 100352 B
  short* sO = smem;
  #pragma unroll
  for (int ct = 0; ct < 3; ++ct) {
    int col = gc[ct];
    float sc = bng[col] * rsqrtf(bnv[col] + BN_EPS);
    float sh = bnb[col] - bnm[col] * sc;
    #pragma unroll
    for (int rt = 0; rt < 4; ++rt)
      #pragma unroll
      for (int rg = 0; rg < 4; ++rg) {
        float xv = acc[rt][ct][rg] * sc + sh;
        if constexpr (EPI == 0)
          xv = xv > 0.f ? xv : expm1f(xv);
        else
          xv = fmaxf(xv, 0.f);
        __hip_bfloat16 bv = __float2bfloat16(xv);
        sO[(wr * 64 + rt * 16 + quad * 4 + rg) * OS + col] = *(short*)&bv;
      }
  }
  __syncthreads();

  if constexpr (FINAL) {
    // fused 384 -> 3 projection from LDS; 384 threads: row = t&127, o = t>>7
    if (t < 384) {
      int row = t & 127, o = t >> 7;
      int grow = row0 + row;
      if (grow < N_NODES) {
        float s = 0.f;
        #pragma unroll
        for (int kb = 0; kb < 48; ++kb) {
          short8 hv = *(const short8*)&sO[row * OS + kb * 8];
          #pragma unroll
          for (int j = 0; j < 8; ++j) s += bf16f(hv[j]) * W3[o * HID + kb * 8 + j];
        }
        out3[grow * OUT_DIM + o] = s + b3[o];
      }
    }
  } else {
    // 128 rows x 768 B out; 48 16B-chunks per row; 1024 thr x 6 chunks
    #pragma unroll
    for (int it = 0; it < 6; ++it) {
      int e = t + it * 1024;
      int row = e / 48, cs = e % 48;
      int grow = row0 + row;
      if (grow < N_NODES) {
        uint4 v = *(const uint4*)&sO[row * OS + cs * 8];
        *(uint4*)(out + (size_t)grow * HID + cs * 8) = v;
      }
    }
  }
}

// ------------------------- launcher -------------------------

extern "C" void kernel_launch(void* const* d_in, const int* in_sizes, int n_in,
                              void* d_out, int out_size, void* d_ws, size_t ws_size,
                              hipStream_t stream) {
  const float* x = (const float*)d_in[0];
  const int* ei = (const int*)d_in[1];
  const int* src = ei;
  const int* dst = ei + N_EDGES;
  const float* W_l0 = (const float*)d_in[2];
  const float* b_l0 = (const float*)d_in[3];
  const float* W_r0 = (const float*)d_in[4];
  const float* W_l = (const float*)d_in[5];
  const float* b_l = (const float*)d_in[6];
  const float* W_r = (const float*)d_in[7];
  const float* bn_g = (const float*)d_in[8];
  const float* bn_b = (const float*)d_in[9];
  const float* bn_m = (const float*)d_in[10];
  const float* bn_v = (const float*)d_in[11];
  const float* Wp0 = (const float*)d_in[12];
  const float* bp0 = (const float*)d_in[13];
  const float* Wp1 = (const float*)d_in[14];
  const float* bp1 = (const float*)d_in[15];
  const float* Wp2 = (const float*)d_in[16];
  const float* bp2 = (const float*)d_in[17];
  const float* pbn_g = (const float*)d_in[18];
  const float* pbn_b = (const float*)d_in[19];
  const float* pbn_m = (const float*)d_in[20];
  const float* pbn_v = (const float*)d_in[21];

  char* ws = (char*)d_ws;
  size_t off = 0;
  auto walloc = [&](size_t bytes) -> void* {
    void* p = ws + off;
    off = (off + bytes + 255) & ~(size_t)255;
    return p;
  };
  __hip_bfloat16* h   = (__hip_bfloat16*)walloc((size_t)N_NODES * HID * 2);  // 76.8 MB
  __hip_bfloat16* agg = (__hip_bfloat16*)walloc((size_t)N_NODES * HID * 2);  // 76.8 MB
  float* agg10 = (float*)agg;  // 4 MB fp32 overlay; agg not used until layer 1
  __hip_bfloat16* X2  = (__hip_bfloat16*)walloc((size_t)N_NODES * 64 * 2);   // 12.8 MB
  __hip_bfloat16* W2  = (__hip_bfloat16*)walloc((size_t)HID * 64 * 2);
  __hip_bfloat16* WlB  = (__hip_bfloat16*)walloc((size_t)(T_LAYERS - 1) * HID * HID * 2);
  __hip_bfloat16* WrB  = (__hip_bfloat16*)walloc((size_t)(T_LAYERS - 1) * HID * HID * 2);
  __hip_bfloat16* Wp0B = (__hip_bfloat16*)walloc((size_t)HID * HID * 2);
  __hip_bfloat16* Wp1B = (__hip_bfloat16*)walloc((size_t)HID * HID * 2);
  int* cnt     = (int*)walloc((size_t)N_NODES * 4);
  int* row_off = (int*)walloc((size_t)(N_NODES + 1) * 4);
  int* cursor  = (int*)walloc((size_t)N_NODES * 4);
  int* csr     = (int*)walloc((size_t)N_EDGES * 4);
  int* bsum    = (int*)walloc(4096);

  hipMemsetAsync(cnt, 0, (size_t)N_NODES * 4, stream);
  hipMemsetAsync(cursor, 0, (size_t)N_NODES * 4, stream);

  // weight prepack
  const int NW = (T_LAYERS - 1) * HID * HID;
  conv_k<<<(NW + 255) / 256, 256, 0, stream>>>(W_l, WlB, NW);
  conv_k<<<(NW + 255) / 256, 256, 0, stream>>>(W_r, WrB, NW);
  conv_k<<<(HID * HID + 255) / 256, 256, 0, stream>>>(Wp0, Wp0B, HID * HID);
  conv_k<<<(HID * HID + 255) / 256, 256, 0, stream>>>(Wp1, Wp1B, HID * HID);
  packw0_k<<<(HID * 64 + 255) / 256, 256, 0, stream>>>(W_l0, W_r0, W2);

  // CSR build
  count_k<<<(N_EDGES + 255) / 256, 256, 0, stream>>>(dst, cnt, N_EDGES);
  int P = (N_NODES + 1 + 1023) / 1024;
  scan_partial_k<<<P, 1024, 0, stream>>>(cnt, bsum, N_NODES);
  scan_small_k<<<1, 1024, 0, stream>>>(bsum, P);
  scan_final_k<<<P, 1024, 0, stream>>>(cnt, bsum, row_off, N_NODES);
  fill_k<<<(N_EDGES + 255) / 256, 256, 0, stream>>>(src, dst, row_off, cursor, csr, N_EDGES);

  const int GB = (N_NODES + 127) / 128;  // 782 row-blocks (BM=128)

  // layer 0: agg10 -> pack -> MFMA GEMM (K=64: [x|agg10|pad] x [Wr0|Wl0|pad])
  agg10_k<<<(N_NODES + 7) / 8, 256, 0, stream>>>(x, row_off, csr, agg10, N_NODES);
  pack0_k<<<(N_NODES * 64 + 255) / 256, 256, 0, stream>>>(x, agg10, X2, N_NODES);
  mfma_gemm_k<64, false, 0, false><<<GB, 1024, 0, stream>>>(
      X2, W2, nullptr, nullptr, b_l0, bn_g, bn_b, bn_m, bn_v, h,
      nullptr, nullptr, nullptr);

  // layers 1..4 (dual MFMA GEMM, in-place h update)
  for (int t = 1; t < T_LAYERS; ++t) {
    aggv_k<<<(N_NODES + 3) / 4, 256, 0, stream>>>(h, row_off, csr, agg, N_NODES);
    mfma_gemm_k<HID, true, 0, false><<<GB, 1024, 0, stream>>>(
        agg, WlB + (size_t)(t - 1) * HID * HID,
        h,   WrB + (size_t)(t - 1) * HID * HID,
        b_l + (size_t)(t - 1) * HID,
        bn_g + (size_t)t * HID, bn_b + (size_t)t * HID,
        bn_m + (size_t)t * HID, bn_v + (size_t)t * HID,
        h, nullptr, nullptr, nullptr);
  }

  // projection MLP: proj0 in-place on h; proj1 fused with the 384->3 output
  mfma_gemm_k<HID, false, 1, false><<<GB, 1024, 0, stream>>>(
      h, Wp0B, nullptr, nullptr, bp0, pbn_g, pbn_b, pbn_m, pbn_v, h,
      nullptr, nullptr, nullptr);
  mfma_gemm_k<HID, false, 1, true><<<GB, 1024, 0, stream>>>(
      h, Wp1B, nullptr, nullptr, bp1, pbn_g + HID, pbn_b + HID, pbn_m + HID, pbn_v + HID, h,
      Wp2, bp2, (float*)d_out);
}

// Round 9
// 1087.455 us; speedup vs baseline: 1.2036x; 1.0390x over previous
//
#include <hip/hip_runtime.h>
#include <hip/hip_bf16.h>

#define N_NODES 100000
#define N_EDGES 300000
#define IN_DIM 10
#define HID 384
#define OUT_DIM 3
#define T_LAYERS 5
#define BN_EPS 1e-5f

typedef __attribute__((ext_vector_type(8))) short short8;
typedef __attribute__((ext_vector_type(4))) float floatx4;

__device__ __forceinline__ float bf16f(short v) {
  return __uint_as_float(((unsigned)(unsigned short)v) << 16);
}

// async global->LDS, 16 B per lane; dst is wave-uniform base, lane l lands at
// dst + l*16 (linear). Swizzle lives on the SOURCE address (m173 pattern).
__device__ __forceinline__ void gld_lds16(const void* g, void* l) {
  __builtin_amdgcn_global_load_lds(
      (const __attribute__((address_space(1))) void*)g,
      (__attribute__((address_space(3))) void*)l, 16, 0, 0);
}

// ------------------------- CSR build -------------------------

__global__ void count_k(const int* __restrict__ dst, int* __restrict__ cnt, int E) {
  int e = blockIdx.x * blockDim.x + threadIdx.x;
  if (e < E) atomicAdd(&cnt[dst[e]], 1);
}

__global__ void scan_partial_k(const int* __restrict__ cnt, int* __restrict__ bsum, int n) {
  int t = threadIdx.x;
  int i = blockIdx.x * 1024 + t;
  int v = (i < n) ? cnt[i] : 0;
  #pragma unroll
  for (int off = 1; off < 64; off <<= 1) v += __shfl_xor(v, off);
  __shared__ int ws[16];
  if ((t & 63) == 0) ws[t >> 6] = v;
  __syncthreads();
  if (t == 0) {
    int s = 0;
    #pragma unroll
    for (int w = 0; w < 16; ++w) s += ws[w];
    bsum[blockIdx.x] = s;
  }
}

__global__ void scan_small_k(int* __restrict__ bsum, int P) {
  __shared__ int s[1024];
  int t = threadIdx.x;
  int v = (t < P) ? bsum[t] : 0;
  s[t] = v;
  __syncthreads();
  for (int off = 1; off < 1024; off <<= 1) {
    int add = (t >= off) ? s[t - off] : 0;
    __syncthreads();
    s[t] += add;
    __syncthreads();
  }
  if (t < P) bsum[t] = s[t] - v;  // exclusive block-prefix
}

__global__ void scan_final_k(const int* __restrict__ cnt, const int* __restrict__ bsum,
                             int* __restrict__ row_off, int n) {
  int t = threadIdx.x, lane = t & 63, wv = t >> 6;
  int i = blockIdx.x * 1024 + t;
  int v = (i < n) ? cnt[i] : 0;
  int x = v;
  #pragma unroll
  for (int off = 1; off < 64; off <<= 1) {
    int y = __shfl_up(x, off);
    if (lane >= off) x += y;
  }
  __shared__ int ws[16];
  if (lane == 63) ws[wv] = x;
  __syncthreads();
  if (t == 0) {
    int a = 0;
    #pragma unroll
    for (int w = 0; w < 16; ++w) { int tmp = ws[w]; ws[w] = a; a += tmp; }
  }
  __syncthreads();
  int excl = (x - v) + ws[wv] + bsum[blockIdx.x];
  if (i <= n) row_off[i] = excl;
}

__global__ void fill_k(const int* __restrict__ src, const int* __restrict__ dst,
                       const int* __restrict__ row_off, int* __restrict__ cursor,
                       int* __restrict__ csr, int E) {
  int e = blockIdx.x * blockDim.x + threadIdx.x;
  if (e < E) {
    int d = dst[e];
    int pos = atomicAdd(&cursor[d], 1);
    csr[row_off[d] + pos] = src[e];
  }
}

// ------------------------- prepack kernels -------------------------

__global__ void conv_k(const float* __restrict__ src, __hip_bfloat16* __restrict__ dst, int n) {
  int i = blockIdx.x * blockDim.x + threadIdx.x;
  if (i < n) dst[i] = __float2bfloat16(src[i]);
}

// X2[n][64] = { x[n][0..10) , agg10[n][0..10) , 0 pad }
__global__ void pack0_k(const float* __restrict__ x, const float* __restrict__ agg10,
                        __hip_bfloat16* __restrict__ X2, int n) {
  int i = blockIdx.x * blockDim.x + threadIdx.x;
  if (i < n * 64) {
    int node = i >> 6, k = i & 63;
    float v = (k < IN_DIM) ? x[node * IN_DIM + k]
              : (k < 2 * IN_DIM) ? agg10[node * IN_DIM + (k - IN_DIM)] : 0.f;
    X2[i] = __float2bfloat16(v);
  }
}

// W2[o][64] = { W_r0 (pairs x) , W_l0 (pairs agg10) , 0 pad }
__global__ void packw0_k(const float* __restrict__ Wl, const float* __restrict__ Wr,
                         __hip_bfloat16* __restrict__ W2) {
  int i = blockIdx.x * blockDim.x + threadIdx.x;
  if (i < HID * 64) {
    int o = i >> 6, k = i & 63;
    float v = (k < IN_DIM) ? Wr[o * IN_DIM + k]
              : (k < 2 * IN_DIM) ? Wl[o * IN_DIM + (k - IN_DIM)]
              : 0.f;
    W2[i] = __float2bfloat16(v);
  }
}

// ------------------------- aggregation -------------------------

__global__ void agg10_k(const float* __restrict__ x, const int* __restrict__ row_off,
                        const int* __restrict__ csr, float* __restrict__ agg10, int n) {
  int sub = threadIdx.x >> 5;
  int lane = threadIdx.x & 31;
  int node = blockIdx.x * 8 + sub;
  if (node >= n) return;
  int s = row_off[node], e = row_off[node + 1];
  if (lane < IN_DIM) {
    float acc = 0.f;
    for (int j = s; j < e; ++j) acc += x[csr[j] * IN_DIM + lane];
    float c = (float)max(e - s, 1);
    agg10[node * IN_DIM + lane] = acc / c;
  }
}

// F=384 mean aggregation: one wave per node, lanes 0..47 hold 8 bf16 cols each.
// Kept SEPARATE (r13 post-mortem: fusing the gather into the GEMM traps it
// behind a block barrier; standalone it gets full TLP latency hiding).
__global__ __launch_bounds__(256) void aggv_k(const __hip_bfloat16* __restrict__ h,
                                              const int* __restrict__ row_off,
                                              const int* __restrict__ csr,
                                              __hip_bfloat16* __restrict__ agg, int n) {
  int node = blockIdx.x * 4 + (threadIdx.x >> 6);
  if (node >= n) return;
  int lane = threadIdx.x & 63;
  if (lane >= 48) return;
  int s = row_off[node], e = row_off[node + 1];
  float acc[8] = {0.f, 0.f, 0.f, 0.f, 0.f, 0.f, 0.f, 0.f};
  for (int j = s; j < e; ++j) {
    const uint4 v = *(const uint4*)(h + (size_t)csr[j] * HID + lane * 8);
    uint u0 = v.x, u1 = v.y, u2 = v.z, u3 = v.w;
    acc[0] += __uint_as_float(u0 << 16);
    acc[1] += __uint_as_float(u0 & 0xffff0000u);
    acc[2] += __uint_as_float(u1 << 16);
    acc[3] += __uint_as_float(u1 & 0xffff0000u);
    acc[4] += __uint_as_float(u2 << 16);
    acc[5] += __uint_as_float(u2 & 0xffff0000u);
    acc[6] += __uint_as_float(u3 << 16);
    acc[7] += __uint_as_float(u3 & 0xffff0000u);
  }
  float invc = 1.f / (float)max(e - s, 1);
  uint out[4];
  #pragma unroll
  for (int q = 0; q < 4; ++q) {
    __hip_bfloat16 lo = __float2bfloat16(acc[2 * q] * invc);
    __hip_bfloat16 hi = __float2bfloat16(acc[2 * q + 1] * invc);
    out[q] = (uint)(*(unsigned short*)&lo) | ((uint)(*(unsigned short*)&hi) << 16);
  }
  *(uint4*)(agg + (size_t)node * HID + lane * 8) = make_uint4(out[0], out[1], out[2], out[3]);
}

// ------------------------- MFMA GEMM, fused epilogue -------------------------
// out[i, col] = sum_k A1[i,k]*B1[col,k] (+ A2[i,k]*B2[col,k]) + bias[col]
// r15 = r12 (the measured best: 136us dual, 1045us total) + register trims
// to shrink the ~12-dword/thread scratch spill (WRITE 112.5 vs 75 MB ideal):
//  * ADDRESSING IDENTITY: in bOff[it], col = (wv*6+it)*8 + (lane>>3) so
//    col&7 = (lane>>3)&7 is INDEPENDENT of it -> the XOR granule is the same
//    for all 6 B-staging instrs, and bOff[it] = bOff0 + it*8*KTOT where
//    it*8*KTOT is a compile-time constant folded into the SGPR address side.
//    6 VGPRs of B addressing -> 1.  Same for epilogue cols: gcBase + ct*16.
//  * Everything else byte-identical to r12: BM=64, 512 thr, 8 waves,
//    2 blocks/CU, A double-buffer + counted vmcnt(1), B distance-0,
//    raw s_barrier x2/chunk, acc[4][3].
//  * r14 post-mortem (BM=128, both-dbuf, vmcnt(4), 1 blk/CU): 152us — worse.
//    Barrier-ganging 16 waves + losing the co-resident block cost more than
//    the removed B-latency. r12's shape is the local optimum of this family.
template <int KTOT, bool DUAL, int EPI, bool FINAL>
__global__ __launch_bounds__(512, 4) void mfma_gemm_k(
    const __hip_bfloat16* __restrict__ A1, const __hip_bfloat16* __restrict__ B1,
    const __hip_bfloat16* __restrict__ A2, const __hip_bfloat16* __restrict__ B2,
    const float* __restrict__ bias,
    const float* __restrict__ bng, const float* __restrict__ bnb,
    const float* __restrict__ bnm, const float* __restrict__ bnv,
    __hip_bfloat16* __restrict__ out,
    const float* __restrict__ W3, const float* __restrict__ b3,
    float* __restrict__ out3) {
  // [0..4096)   : sA parity 0   (64 rows x 64 k)
  // [4096..8192): sA parity 1
  // [8192..32768): sB (384 cols x 64 k)
  // epilogue reuses [0..25088) as sO[64][392] and [0..512) floats as red
  __shared__ alignas(16) short smem[32768];  // 65536 B
  short* sB = smem + 8192;

  const int t = threadIdx.x;
  const int lane = t & 63;
  const int wv = t >> 6;        // 0..7
  const int n16 = lane & 15;
  const int quad = lane >> 4;
  const int row0 = blockIdx.x * 64;

  // ---- staging geometry (per-thread constant source offsets) ----
  // A: one gld_lds per wave covers rows wv*8..wv*8+7; LDS short idx =
  //    bufbase + wv*512 + lane*8 -> row = wv*8 + (lane>>3), slot = lane&7;
  //    source granule g = slot ^ (row&7) (inverse of the read swizzle).
  const int aRow = t >> 3;                  // 0..63
  const int aG = (t & 7) ^ (aRow & 7);
  const int aOff = min(row0 + aRow, N_NODES - 1) * KTOT + aG * 8;  // elements
  // B: 6 gld_lds per wave; instr it covers cols (wv*6+it)*8 .. +7.
  // col&7 == (lane>>3)&7 for every it, so one per-lane base suffices; the
  // it-dependent part (it*8*KTOT) is a compile-time uniform (SGPR side).
  const int bCol0 = wv * 48 + (lane >> 3);
  const int bG = (lane & 7) ^ ((lane >> 3) & 7);
  const int bOff0 = bCol0 * KTOT + bG * 8;  // elements

  floatx4 acc[4][3];
  #pragma unroll
  for (int rt = 0; rt < 4; ++rt)
    #pragma unroll
    for (int ct = 0; ct < 3; ++ct) acc[rt][ct] = (floatx4)0.f;

  constexpr int KCH = KTOT / 64;
  constexpr int NCH = DUAL ? 2 * KCH : KCH;

  // prologue: prefetch A(0) into parity 0 (chunk 0 is always A1, kc=0)
  gld_lds16(A1 + aOff, smem + wv * 512);

  for (int c = 0; c < NCH; ++c) {
    const __hip_bfloat16* Bp;
    int kc;
    if (!DUAL || c < KCH) { Bp = B1; kc = c * 64; }
    else                  { Bp = B2; kc = (c - KCH) * 64; }

    // stage B(c): 6 gld_lds per wave (48 KB total)
    #pragma unroll
    for (int it = 0; it < 6; ++it)
      gld_lds16(Bp + bOff0 + (it * 8 * KTOT + kc), sB + (wv * 6 + it) * 512);

    // prefetch A(c+1) into the other parity (stays in flight across barrier)
    if (c + 1 < NCH) {
      const __hip_bfloat16* Ap;
      int kn;
      int cn = c + 1;
      if (!DUAL || cn < KCH) { Ap = A1; kn = cn * 64; }
      else                   { Ap = A2; kn = (cn - KCH) * 64; }
      gld_lds16(Ap + aOff + kn, smem + (cn & 1) * 4096 + wv * 512);
      asm volatile("s_waitcnt vmcnt(1)" ::: "memory");  // A(c)+B(c) done
    } else {
      asm volatile("s_waitcnt vmcnt(0)" ::: "memory");  // drain everything
    }
    __builtin_amdgcn_sched_barrier(0);
    __builtin_amdgcn_s_barrier();   // staged data visible to all waves

    // compute chunk c from parity c&1
    const short* sAc = smem + (c & 1) * 4096;
    #pragma unroll
    for (int kh = 0; kh < 2; ++kh) {
      short8 af[4];
      int g = kh * 4 + quad;
      #pragma unroll
      for (int rt = 0; rt < 4; ++rt) {
        int r = rt * 16 + n16;
        af[rt] = *(const short8*)&sAc[r * 64 + ((g ^ (r & 7)) * 8)];
      }
      #pragma unroll
      for (int ct = 0; ct < 3; ++ct) {
        int cl = wv * 48 + ct * 16 + n16;
        short8 bf = *(const short8*)&sB[cl * 64 + ((g ^ (cl & 7)) * 8)];
        #pragma unroll
        for (int rt = 0; rt < 4; ++rt)
          acc[rt][ct] = __builtin_amdgcn_mfma_f32_16x16x32_bf16(af[rt], bf, acc[rt][ct], 0, 0, 0);
      }
    }
    __builtin_amdgcn_s_barrier();   // all reads of sB/sA done before re-stage
    asm volatile("" ::: "memory");
  }

  // ---- epilogue ----
  const int gcBase = wv * 48 + n16;  // col = gcBase + ct*16 (compile-time mult)
  #pragma unroll
  for (int ct = 0; ct < 3; ++ct) {
    float bs = bias[gcBase + ct * 16];
    #pragma unroll
    for (int rt = 0; rt < 4; ++rt)
      #pragma unroll
      for (int rg = 0; rg < 4; ++rg) acc[rt][ct][rg] += bs;
  }

  if constexpr (EPI == 0) {
    // row L2 norm: 16-lane shfl partials, cross-wave (8 waves) via LDS
    float* red = (float*)smem;  // 512 floats
    #pragma unroll
    for (int rt = 0; rt < 4; ++rt)
      #pragma unroll
      for (int rg = 0; rg < 4; ++rg) {
        float s = 0.f;
        #pragma unroll
        for (int ct = 0; ct < 3; ++ct) s += acc[rt][ct][rg] * acc[rt][ct][rg];
        #pragma unroll
        for (int off = 1; off < 16; off <<= 1) s += __shfl_xor(s, off);
        if (n16 == 0) red[wv * 64 + rt * 16 + quad * 4 + rg] = s;
      }
    __syncthreads();
    #pragma unroll
    for (int rt = 0; rt < 4; ++rt) {
      float inv[4];
      #pragma unroll
      for (int rg = 0; rg < 4; ++rg) {
        int rl = rt * 16 + quad * 4 + rg;
        float ss = 0.f;
        #pragma unroll
        for (int w = 0; w < 8; ++w) ss += red[w * 64 + rl];
        inv[rg] = 1.f / fmaxf(sqrtf(ss), 1e-12f);
      }
      #pragma unroll
      for (int ct = 0; ct < 3; ++ct)
        #pragma unroll
        for (int rg = 0; rg < 4; ++rg) acc[rt][ct][rg] *= inv[rg];
    }
    __syncthreads();  // red reads done before smem reused as sO
  }

  // BN + activation, pack bf16 into LDS (row stride 392 shorts)
  constexpr int OS = 392;
  short* sO = smem;
  #pragma unroll
  for (int ct = 0; ct < 3; ++ct) {
    int col = gcBase + ct * 16;
    float sc = bng[col] * rsqrtf(bnv[col] + BN_EPS);
    float sh = bnb[col] - bnm[col] * sc;
    #pragma unroll
    for (int rt = 0; rt < 4; ++rt)
      #pragma unroll
      for (int rg = 0; rg < 4; ++rg) {
        float xv = acc[rt][ct][rg] * sc + sh;
        if constexpr (EPI == 0)
          xv = xv > 0.f ? xv : expm1f(xv);
        else
          xv = fmaxf(xv, 0.f);
        __hip_bfloat16 bv = __float2bfloat16(xv);
        sO[(rt * 16 + quad * 4 + rg) * OS + col] = *(short*)&bv;
      }
  }
  __syncthreads();

  if constexpr (FINAL) {
    // fused 384 -> 3 projection from LDS; thread (row = t&63, o = t>>6), t<192
    if (t < 192) {
      int row = t & 63, o = t >> 6;
      int grow = row0 + row;
      if (grow < N_NODES) {
        float s = 0.f;
        #pragma unroll
        for (int kb = 0; kb < 48; ++kb) {
          short8 hv = *(const short8*)&sO[row * OS + kb * 8];
          #pragma unroll
          for (int j = 0; j < 8; ++j) s += bf16f(hv[j]) * W3[o * HID + kb * 8 + j];
        }
        out3[grow * OUT_DIM + o] = s + b3[o];
      }
    }
  } else {
    // 64 rows x 768 B out; 48 16B-chunks per row; 512 thr x 6 chunks
    #pragma unroll
    for (int it = 0; it < 6; ++it) {
      int e = t + it * 512;
      int row = e / 48, cs = e % 48;
      int grow = row0 + row;
      if (grow < N_NODES) {
        uint4 v = *(const uint4*)&sO[row * OS + cs * 8];
        *(uint4*)(out + (size_t)grow * HID + cs * 8) = v;
      }
    }
  }
}

// ------------------------- launcher -------------------------

extern "C" void kernel_launch(void* const* d_in, const int* in_sizes, int n_in,
                              void* d_out, int out_size, void* d_ws, size_t ws_size,
                              hipStream_t stream) {
  const float* x = (const float*)d_in[0];
  const int* ei = (const int*)d_in[1];
  const int* src = ei;
  const int* dst = ei + N_EDGES;
  const float* W_l0 = (const float*)d_in[2];
  const float* b_l0 = (const float*)d_in[3];
  const float* W_r0 = (const float*)d_in[4];
  const float* W_l = (const float*)d_in[5];
  const float* b_l = (const float*)d_in[6];
  const float* W_r = (const float*)d_in[7];
  const float* bn_g = (const float*)d_in[8];
  const float* bn_b = (const float*)d_in[9];
  const float* bn_m = (const float*)d_in[10];
  const float* bn_v = (const float*)d_in[11];
  const float* Wp0 = (const float*)d_in[12];
  const float* bp0 = (const float*)d_in[13];
  const float* Wp1 = (const float*)d_in[14];
  const float* bp1 = (const float*)d_in[15];
  const float* Wp2 = (const float*)d_in[16];
  const float* bp2 = (const float*)d_in[17];
  const float* pbn_g = (const float*)d_in[18];
  const float* pbn_b = (const float*)d_in[19];
  const float* pbn_m = (const float*)d_in[20];
  const float* pbn_v = (const float*)d_in[21];

  char* ws = (char*)d_ws;
  size_t off = 0;
  auto walloc = [&](size_t bytes) -> void* {
    void* p = ws + off;
    off = (off + bytes + 255) & ~(size_t)255;
    return p;
  };
  __hip_bfloat16* h   = (__hip_bfloat16*)walloc((size_t)N_NODES * HID * 2);  // 76.8 MB
  __hip_bfloat16* agg = (__hip_bfloat16*)walloc((size_t)N_NODES * HID * 2);  // 76.8 MB
  float* agg10 = (float*)agg;  // 4 MB fp32 overlay; agg not used until layer 1
  __hip_bfloat16* X2  = (__hip_bfloat16*)walloc((size_t)N_NODES * 64 * 2);   // 12.8 MB
  __hip_bfloat16* W2  = (__hip_bfloat16*)walloc((size_t)HID * 64 * 2);
  __hip_bfloat16* WlB  = (__hip_bfloat16*)walloc((size_t)(T_LAYERS - 1) * HID * HID * 2);
  __hip_bfloat16* WrB  = (__hip_bfloat16*)walloc((size_t)(T_LAYERS - 1) * HID * HID * 2);
  __hip_bfloat16* Wp0B = (__hip_bfloat16*)walloc((size_t)HID * HID * 2);
  __hip_bfloat16* Wp1B = (__hip_bfloat16*)walloc((size_t)HID * HID * 2);
  int* cnt     = (int*)walloc((size_t)N_NODES * 4);
  int* row_off = (int*)walloc((size_t)(N_NODES + 1) * 4);
  int* cursor  = (int*)walloc((size_t)N_NODES * 4);
  int* csr     = (int*)walloc((size_t)N_EDGES * 4);
  int* bsum    = (int*)walloc(4096);

  hipMemsetAsync(cnt, 0, (size_t)N_NODES * 4, stream);
  hipMemsetAsync(cursor, 0, (size_t)N_NODES * 4, stream);

  // weight prepack
  const int NW = (T_LAYERS - 1) * HID * HID;
  conv_k<<<(NW + 255) / 256, 256, 0, stream>>>(W_l, WlB, NW);
  conv_k<<<(NW + 255) / 256, 256, 0, stream>>>(W_r, WrB, NW);
  conv_k<<<(HID * HID + 255) / 256, 256, 0, stream>>>(Wp0, Wp0B, HID * HID);
  conv_k<<<(HID * HID + 255) / 256, 256, 0, stream>>>(Wp1, Wp1B, HID * HID);
  packw0_k<<<(HID * 64 + 255) / 256, 256, 0, stream>>>(W_l0, W_r0, W2);

  // CSR build
  count_k<<<(N_EDGES + 255) / 256, 256, 0, stream>>>(dst, cnt, N_EDGES);
  int P = (N_NODES + 1 + 1023) / 1024;
  scan_partial_k<<<P, 1024, 0, stream>>>(cnt, bsum, N_NODES);
  scan_small_k<<<1, 1024, 0, stream>>>(bsum, P);
  scan_final_k<<<P, 1024, 0, stream>>>(cnt, bsum, row_off, N_NODES);
  fill_k<<<(N_EDGES + 255) / 256, 256, 0, stream>>>(src, dst, row_off, cursor, csr, N_EDGES);

  const int GB = (N_NODES + 63) / 64;  // 1563 row-blocks

  // layer 0: agg10 -> pack -> MFMA GEMM (K=64: [x|agg10|pad] x [Wr0|Wl0|pad])
  agg10_k<<<(N_NODES + 7) / 8, 256, 0, stream>>>(x, row_off, csr, agg10, N_NODES);
  pack0_k<<<(N_NODES * 64 + 255) / 256, 256, 0, stream>>>(x, agg10, X2, N_NODES);
  mfma_gemm_k<64, false, 0, false><<<GB, 512, 0, stream>>>(
      X2, W2, nullptr, nullptr, b_l0, bn_g, bn_b, bn_m, bn_v, h,
      nullptr, nullptr, nullptr);

  // layers 1..4 (dual MFMA GEMM, in-place h update)
  for (int t = 1; t < T_LAYERS; ++t) {
    aggv_k<<<(N_NODES + 3) / 4, 256, 0, stream>>>(h, row_off, csr, agg, N_NODES);
    mfma_gemm_k<HID, true, 0, false><<<GB, 512, 0, stream>>>(
        agg, WlB + (size_t)(t - 1) * HID * HID,
        h,   WrB + (size_t)(t - 1) * HID * HID,
        b_l + (size_t)(t - 1) * HID,
        bn_g + (size_t)t * HID, bn_b + (size_t)t * HID,
        bn_m + (size_t)t * HID, bn_v + (size_t)t * HID,
        h, nullptr, nullptr, nullptr);
  }

  // projection MLP: proj0 in-place on h; proj1 fused with the 384->3 output
  mfma_gemm_k<HID, false, 1, false><<<GB, 512, 0, stream>>>(
      h, Wp0B, nullptr, nullptr, bp0, pbn_g, pbn_b, pbn_m, pbn_v, h,
      nullptr, nullptr, nullptr);
  mfma_gemm_k<HID, false, 1, true><<<GB, 512, 0, stream>>>(
      h, Wp1B, nullptr, nullptr, bp1, pbn_g + HID, pbn_b + HID, pbn_m + HID, pbn_v + HID, h,
      Wp2, bp2, (float*)d_out);
}

// Round 10
// 888.407 us; speedup vs baseline: 1.4732x; 1.2241x over previous
//
#include <hip/hip_runtime.h>
#include <hip/hip_bf16.h>

#define N_NODES 100000
#define N_EDGES 300000
#define IN_DIM 10
#define HID 384
#define OUT_DIM 3
#define T_LAYERS 5
#define BN_EPS 1e-5f

typedef __attribute__((ext_vector_type(8))) short short8;
typedef __attribute__((ext_vector_type(4))) float floatx4;

__device__ __forceinline__ float bf16f(short v) {
  return __uint_as_float(((unsigned)(unsigned short)v) << 16);
}

// async global->LDS, 16 B per lane; dst is wave-uniform base, lane l lands at
// dst + l*16 (linear). Swizzle lives on the SOURCE address (m173 pattern).
__device__ __forceinline__ void gld_lds16(const void* g, void* l) {
  __builtin_amdgcn_global_load_lds(
      (const __attribute__((address_space(1))) void*)g,
      (__attribute__((address_space(3))) void*)l, 16, 0, 0);
}

// ------------------------- CSR build -------------------------

__global__ void count_k(const int* __restrict__ dst, int* __restrict__ cnt, int E) {
  int e = blockIdx.x * blockDim.x + threadIdx.x;
  if (e < E) atomicAdd(&cnt[dst[e]], 1);
}

__global__ void scan_partial_k(const int* __restrict__ cnt, int* __restrict__ bsum, int n) {
  int t = threadIdx.x;
  int i = blockIdx.x * 1024 + t;
  int v = (i < n) ? cnt[i] : 0;
  #pragma unroll
  for (int off = 1; off < 64; off <<= 1) v += __shfl_xor(v, off);
  __shared__ int ws[16];
  if ((t & 63) == 0) ws[t >> 6] = v;
  __syncthreads();
  if (t == 0) {
    int s = 0;
    #pragma unroll
    for (int w = 0; w < 16; ++w) s += ws[w];
    bsum[blockIdx.x] = s;
  }
}

__global__ void scan_small_k(int* __restrict__ bsum, int P) {
  __shared__ int s[1024];
  int t = threadIdx.x;
  int v = (t < P) ? bsum[t] : 0;
  s[t] = v;
  __syncthreads();
  for (int off = 1; off < 1024; off <<= 1) {
    int add = (t >= off) ? s[t - off] : 0;
    __syncthreads();
    s[t] += add;
    __syncthreads();
  }
  if (t < P) bsum[t] = s[t] - v;  // exclusive block-prefix
}

__global__ void scan_final_k(const int* __restrict__ cnt, const int* __restrict__ bsum,
                             int* __restrict__ row_off, int n) {
  int t = threadIdx.x, lane = t & 63, wv = t >> 6;
  int i = blockIdx.x * 1024 + t;
  int v = (i < n) ? cnt[i] : 0;
  int x = v;
  #pragma unroll
  for (int off = 1; off < 64; off <<= 1) {
    int y = __shfl_up(x, off);
    if (lane >= off) x += y;
  }
  __shared__ int ws[16];
  if (lane == 63) ws[wv] = x;
  __syncthreads();
  if (t == 0) {
    int a = 0;
    #pragma unroll
    for (int w = 0; w < 16; ++w) { int tmp = ws[w]; ws[w] = a; a += tmp; }
  }
  __syncthreads();
  int excl = (x - v) + ws[wv] + bsum[blockIdx.x];
  if (i <= n) row_off[i] = excl;
}

__global__ void fill_k(const int* __restrict__ src, const int* __restrict__ dst,
                       const int* __restrict__ row_off, int* __restrict__ cursor,
                       int* __restrict__ csr, int E) {
  int e = blockIdx.x * blockDim.x + threadIdx.x;
  if (e < E) {
    int d = dst[e];
    int pos = atomicAdd(&cursor[d], 1);
    csr[row_off[d] + pos] = src[e];
  }
}

// ------------------------- prepack kernels -------------------------

__global__ void conv_k(const float* __restrict__ src, __hip_bfloat16* __restrict__ dst, int n) {
  int i = blockIdx.x * blockDim.x + threadIdx.x;
  if (i < n) dst[i] = __float2bfloat16(src[i]);
}

// X2[n][64] = { x[n][0..10) , agg10[n][0..10) , 0 pad }
__global__ void pack0_k(const float* __restrict__ x, const float* __restrict__ agg10,
                        __hip_bfloat16* __restrict__ X2, int n) {
  int i = blockIdx.x * blockDim.x + threadIdx.x;
  if (i < n * 64) {
    int node = i >> 6, k = i & 63;
    float v = (k < IN_DIM) ? x[node * IN_DIM + k]
              : (k < 2 * IN_DIM) ? agg10[node * IN_DIM + (k - IN_DIM)] : 0.f;
    X2[i] = __float2bfloat16(v);
  }
}

// W2[o][64] = { W_r0 (pairs x) , W_l0 (pairs agg10) , 0 pad }
__global__ void packw0_k(const float* __restrict__ Wl, const float* __restrict__ Wr,
                         __hip_bfloat16* __restrict__ W2) {
  int i = blockIdx.x * blockDim.x + threadIdx.x;
  if (i < HID * 64) {
    int o = i >> 6, k = i & 63;
    float v = (k < IN_DIM) ? Wr[o * IN_DIM + k]
              : (k < 2 * IN_DIM) ? Wl[o * IN_DIM + (k - IN_DIM)]
              : 0.f;
    W2[i] = __float2bfloat16(v);
  }
}

// ------------------------- aggregation -------------------------

__global__ void agg10_k(const float* __restrict__ x, const int* __restrict__ row_off,
                        const int* __restrict__ csr, float* __restrict__ agg10, int n) {
  int sub = threadIdx.x >> 5;
  int lane = threadIdx.x & 31;
  int node = blockIdx.x * 8 + sub;
  if (node >= n) return;
  int s = row_off[node], e = row_off[node + 1];
  if (lane < IN_DIM) {
    float acc = 0.f;
    for (int j = s; j < e; ++j) acc += x[csr[j] * IN_DIM + lane];
    float c = (float)max(e - s, 1);
    agg10[node * IN_DIM + lane] = acc / c;
  }
}

// F=384 mean aggregation: one wave per node, lanes 0..47 hold 8 bf16 cols each.
// Kept SEPARATE (r13 post-mortem: fusing the gather into the GEMM traps it
// behind a block barrier; standalone it gets full TLP latency hiding).
__global__ __launch_bounds__(256) void aggv_k(const __hip_bfloat16* __restrict__ h,
                                              const int* __restrict__ row_off,
                                              const int* __restrict__ csr,
                                              __hip_bfloat16* __restrict__ agg, int n) {
  int node = blockIdx.x * 4 + (threadIdx.x >> 6);
  if (node >= n) return;
  int lane = threadIdx.x & 63;
  if (lane >= 48) return;
  int s = row_off[node], e = row_off[node + 1];
  float acc[8] = {0.f, 0.f, 0.f, 0.f, 0.f, 0.f, 0.f, 0.f};
  for (int j = s; j < e; ++j) {
    const uint4 v = *(const uint4*)(h + (size_t)csr[j] * HID + lane * 8);
    uint u0 = v.x, u1 = v.y, u2 = v.z, u3 = v.w;
    acc[0] += __uint_as_float(u0 << 16);
    acc[1] += __uint_as_float(u0 & 0xffff0000u);
    acc[2] += __uint_as_float(u1 << 16);
    acc[3] += __uint_as_float(u1 & 0xffff0000u);
    acc[4] += __uint_as_float(u2 << 16);
    acc[5] += __uint_as_float(u2 & 0xffff0000u);
    acc[6] += __uint_as_float(u3 << 16);
    acc[7] += __uint_as_float(u3 & 0xffff0000u);
  }
  float invc = 1.f / (float)max(e - s, 1);
  uint out[4];
  #pragma unroll
  for (int q = 0; q < 4; ++q) {
    __hip_bfloat16 lo = __float2bfloat16(acc[2 * q] * invc);
    __hip_bfloat16 hi = __float2bfloat16(acc[2 * q + 1] * invc);
    out[q] = (uint)(*(unsigned short*)&lo) | ((uint)(*(unsigned short*)&hi) << 16);
  }
  *(uint4*)(agg + (size_t)node * HID + lane * 8) = make_uint4(out[0], out[1], out[2], out[3]);
}

// ------------------------- MFMA GEMM, fused epilogue -------------------------
// out[i, col] = sum_k A1[i,k]*B1[col,k] (+ A2[i,k]*B2[col,k]) + bias[col]
// r16 = r15/r12 K-loop (measured best, 136-137us dual) + epilogue VALU diet:
//  * r15 post-mortem: addressing trims didn't move WRITE_SIZE (spill is
//    structural at the 128-reg tier; alt tier = 8 waves/CU = slower; accept).
//  * NEW diagnosis: proj (6 chunks) == dual (12 chunks) == 137us and
//    VALUBusy=42% in a ~50-VALU-ops/chunk K-loop. The EPI-0 epilogue's
//    expm1f (libm poly, ~25 ops, both predication paths paid) x 48 elems
//    ~= 1200 VALU ops/thread — 2x the whole K-loop — serial after the last
//    MFMA. Plus 16x (sqrtf + fdiv) in the norm.
//  * Fix: ELU via __expf (v_exp_f32, ~3 ops) - 1; norm via rsqrtf(fmax).
//    Error << bf16 output rounding (absmax tripwire: must stay ~0.00195).
// Everything else byte-identical to r15.
template <int KTOT, bool DUAL, int EPI, bool FINAL>
__global__ __launch_bounds__(512, 4) void mfma_gemm_k(
    const __hip_bfloat16* __restrict__ A1, const __hip_bfloat16* __restrict__ B1,
    const __hip_bfloat16* __restrict__ A2, const __hip_bfloat16* __restrict__ B2,
    const float* __restrict__ bias,
    const float* __restrict__ bng, const float* __restrict__ bnb,
    const float* __restrict__ bnm, const float* __restrict__ bnv,
    __hip_bfloat16* __restrict__ out,
    const float* __restrict__ W3, const float* __restrict__ b3,
    float* __restrict__ out3) {
  // [0..4096)   : sA parity 0   (64 rows x 64 k)
  // [4096..8192): sA parity 1
  // [8192..32768): sB (384 cols x 64 k)
  // epilogue reuses [0..25088) as sO[64][392] and [0..512) floats as red
  __shared__ alignas(16) short smem[32768];  // 65536 B
  short* sB = smem + 8192;

  const int t = threadIdx.x;
  const int lane = t & 63;
  const int wv = t >> 6;        // 0..7
  const int n16 = lane & 15;
  const int quad = lane >> 4;
  const int row0 = blockIdx.x * 64;

  // ---- staging geometry (per-thread constant source offsets) ----
  const int aRow = t >> 3;                  // 0..63
  const int aG = (t & 7) ^ (aRow & 7);
  const int aOff = min(row0 + aRow, N_NODES - 1) * KTOT + aG * 8;  // elements
  // B: col&7 == (lane>>3)&7 for every it -> one per-lane base; it*8*KTOT is a
  // compile-time uniform folded into the SGPR side.
  const int bCol0 = wv * 48 + (lane >> 3);
  const int bG = (lane & 7) ^ ((lane >> 3) & 7);
  const int bOff0 = bCol0 * KTOT + bG * 8;  // elements

  floatx4 acc[4][3];
  #pragma unroll
  for (int rt = 0; rt < 4; ++rt)
    #pragma unroll
    for (int ct = 0; ct < 3; ++ct) acc[rt][ct] = (floatx4)0.f;

  constexpr int KCH = KTOT / 64;
  constexpr int NCH = DUAL ? 2 * KCH : KCH;

  // prologue: prefetch A(0) into parity 0 (chunk 0 is always A1, kc=0)
  gld_lds16(A1 + aOff, smem + wv * 512);

  for (int c = 0; c < NCH; ++c) {
    const __hip_bfloat16* Bp;
    int kc;
    if (!DUAL || c < KCH) { Bp = B1; kc = c * 64; }
    else                  { Bp = B2; kc = (c - KCH) * 64; }

    // stage B(c): 6 gld_lds per wave (48 KB total)
    #pragma unroll
    for (int it = 0; it < 6; ++it)
      gld_lds16(Bp + bOff0 + (it * 8 * KTOT + kc), sB + (wv * 6 + it) * 512);

    // prefetch A(c+1) into the other parity (stays in flight across barrier)
    if (c + 1 < NCH) {
      const __hip_bfloat16* Ap;
      int kn;
      int cn = c + 1;
      if (!DUAL || cn < KCH) { Ap = A1; kn = cn * 64; }
      else                   { Ap = A2; kn = (cn - KCH) * 64; }
      gld_lds16(Ap + aOff + kn, smem + (cn & 1) * 4096 + wv * 512);
      asm volatile("s_waitcnt vmcnt(1)" ::: "memory");  // A(c)+B(c) done
    } else {
      asm volatile("s_waitcnt vmcnt(0)" ::: "memory");  // drain everything
    }
    __builtin_amdgcn_sched_barrier(0);
    __builtin_amdgcn_s_barrier();   // staged data visible to all waves

    // compute chunk c from parity c&1
    const short* sAc = smem + (c & 1) * 4096;
    #pragma unroll
    for (int kh = 0; kh < 2; ++kh) {
      short8 af[4];
      int g = kh * 4 + quad;
      #pragma unroll
      for (int rt = 0; rt < 4; ++rt) {
        int r = rt * 16 + n16;
        af[rt] = *(const short8*)&sAc[r * 64 + ((g ^ (r & 7)) * 8)];
      }
      #pragma unroll
      for (int ct = 0; ct < 3; ++ct) {
        int cl = wv * 48 + ct * 16 + n16;
        short8 bf = *(const short8*)&sB[cl * 64 + ((g ^ (cl & 7)) * 8)];
        #pragma unroll
        for (int rt = 0; rt < 4; ++rt)
          acc[rt][ct] = __builtin_amdgcn_mfma_f32_16x16x32_bf16(af[rt], bf, acc[rt][ct], 0, 0, 0);
      }
    }
    __builtin_amdgcn_s_barrier();   // all reads of sB/sA done before re-stage
    asm volatile("" ::: "memory");
  }

  // ---- epilogue ----
  const int gcBase = wv * 48 + n16;  // col = gcBase + ct*16 (compile-time mult)
  #pragma unroll
  for (int ct = 0; ct < 3; ++ct) {
    float bs = bias[gcBase + ct * 16];
    #pragma unroll
    for (int rt = 0; rt < 4; ++rt)
      #pragma unroll
      for (int rg = 0; rg < 4; ++rg) acc[rt][ct][rg] += bs;
  }

  if constexpr (EPI == 0) {
    // row L2 norm: 16-lane shfl partials, cross-wave (8 waves) via LDS
    float* red = (float*)smem;  // 512 floats
    #pragma unroll
    for (int rt = 0; rt < 4; ++rt)
      #pragma unroll
      for (int rg = 0; rg < 4; ++rg) {
        float s = 0.f;
        #pragma unroll
        for (int ct = 0; ct < 3; ++ct) s += acc[rt][ct][rg] * acc[rt][ct][rg];
        #pragma unroll
        for (int off = 1; off < 16; off <<= 1) s += __shfl_xor(s, off);
        if (n16 == 0) red[wv * 64 + rt * 16 + quad * 4 + rg] = s;
      }
    __syncthreads();
    #pragma unroll
    for (int rt = 0; rt < 4; ++rt) {
      float inv[4];
      #pragma unroll
      for (int rg = 0; rg < 4; ++rg) {
        int rl = rt * 16 + quad * 4 + rg;
        float ss = 0.f;
        #pragma unroll
        for (int w = 0; w < 8; ++w) ss += red[w * 64 + rl];
        // 1/max(sqrt(ss),1e-12) == rsqrt(max(ss,1e-24)) up to rounding;
        // v_rsq_f32 replaces sqrt + fdiv (~12 VALU ops -> 1).
        inv[rg] = rsqrtf(fmaxf(ss, 1e-24f));
      }
      #pragma unroll
      for (int ct = 0; ct < 3; ++ct)
        #pragma unroll
        for (int rg = 0; rg < 4; ++rg) acc[rt][ct][rg] *= inv[rg];
    }
    __syncthreads();  // red reads done before smem reused as sO
  }

  // BN + activation, pack bf16 into LDS (row stride 392 shorts)
  constexpr int OS = 392;
  short* sO = smem;
  #pragma unroll
  for (int ct = 0; ct < 3; ++ct) {
    int col = gcBase + ct * 16;
    float sc = bng[col] * rsqrtf(bnv[col] + BN_EPS);
    float sh = bnb[col] - bnm[col] * sc;
    #pragma unroll
    for (int rt = 0; rt < 4; ++rt)
      #pragma unroll
      for (int rg = 0; rg < 4; ++rg) {
        float xv = acc[rt][ct][rg] * sc + sh;
        if constexpr (EPI == 0)
          // ELU via v_exp_f32 (~3 ops) instead of expm1f libm poly (~25 ops,
          // both predication paths paid). Error << bf16 output rounding.
          xv = xv > 0.f ? xv : (__expf(xv) - 1.0f);
        else
          xv = fmaxf(xv, 0.f);
        __hip_bfloat16 bv = __float2bfloat16(xv);
        sO[(rt * 16 + quad * 4 + rg) * OS + col] = *(short*)&bv;
      }
  }
  __syncthreads();

  if constexpr (FINAL) {
    // fused 384 -> 3 projection from LDS; thread (row = t&63, o = t>>6), t<192
    if (t < 192) {
      int row = t & 63, o = t >> 6;
      int grow = row0 + row;
      if (grow < N_NODES) {
        float s = 0.f;
        #pragma unroll
        for (int kb = 0; kb < 48; ++kb) {
          short8 hv = *(const short8*)&sO[row * OS + kb * 8];
          #pragma unroll
          for (int j = 0; j < 8; ++j) s += bf16f(hv[j]) * W3[o * HID + kb * 8 + j];
        }
        out3[grow * OUT_DIM + o] = s + b3[o];
      }
    }
  } else {
    // 64 rows x 768 B out; 48 16B-chunks per row; 512 thr x 6 chunks
    #pragma unroll
    for (int it = 0; it < 6; ++it) {
      int e = t + it * 512;
      int row = e / 48, cs = e % 48;
      int grow = row0 + row;
      if (grow < N_NODES) {
        uint4 v = *(const uint4*)&sO[row * OS + cs * 8];
        *(uint4*)(out + (size_t)grow * HID + cs * 8) = v;
      }
    }
  }
}

// ------------------------- launcher -------------------------

extern "C" void kernel_launch(void* const* d_in, const int* in_sizes, int n_in,
                              void* d_out, int out_size, void* d_ws, size_t ws_size,
                              hipStream_t stream) {
  const float* x = (const float*)d_in[0];
  const int* ei = (const int*)d_in[1];
  const int* src = ei;
  const int* dst = ei + N_EDGES;
  const float* W_l0 = (const float*)d_in[2];
  const float* b_l0 = (const float*)d_in[3];
  const float* W_r0 = (const float*)d_in[4];
  const float* W_l = (const float*)d_in[5];
  const float* b_l = (const float*)d_in[6];
  const float* W_r = (const float*)d_in[7];
  const float* bn_g = (const float*)d_in[8];
  const float* bn_b = (const float*)d_in[9];
  const float* bn_m = (const float*)d_in[10];
  const float* bn_v = (const float*)d_in[11];
  const float* Wp0 = (const float*)d_in[12];
  const float* bp0 = (const float*)d_in[13];
  const float* Wp1 = (const float*)d_in[14];
  const float* bp1 = (const float*)d_in[15];
  const float* Wp2 = (const float*)d_in[16];
  const float* bp2 = (const float*)d_in[17];
  const float* pbn_g = (const float*)d_in[18];
  const float* pbn_b = (const float*)d_in[19];
  const float* pbn_m = (const float*)d_in[20];
  const float* pbn_v = (const float*)d_in[21];

  char* ws = (char*)d_ws;
  size_t off = 0;
  auto walloc = [&](size_t bytes) -> void* {
    void* p = ws + off;
    off = (off + bytes + 255) & ~(size_t)255;
    return p;
  };
  __hip_bfloat16* h   = (__hip_bfloat16*)walloc((size_t)N_NODES * HID * 2);  // 76.8 MB
  __hip_bfloat16* agg = (__hip_bfloat16*)walloc((size_t)N_NODES * HID * 2);  // 76.8 MB
  float* agg10 = (float*)agg;  // 4 MB fp32 overlay; agg not used until layer 1
  __hip_bfloat16* X2  = (__hip_bfloat16*)walloc((size_t)N_NODES * 64 * 2);   // 12.8 MB
  __hip_bfloat16* W2  = (__hip_bfloat16*)walloc((size_t)HID * 64 * 2);
  __hip_bfloat16* WlB  = (__hip_bfloat16*)walloc((size_t)(T_LAYERS - 1) * HID * HID * 2);
  __hip_bfloat16* WrB  = (__hip_bfloat16*)walloc((size_t)(T_LAYERS - 1) * HID * HID * 2);
  __hip_bfloat16* Wp0B = (__hip_bfloat16*)walloc((size_t)HID * HID * 2);
  __hip_bfloat16* Wp1B = (__hip_bfloat16*)walloc((size_t)HID * HID * 2);
  int* cnt     = (int*)walloc((size_t)N_NODES * 4);
  int* row_off = (int*)walloc((size_t)(N_NODES + 1) * 4);
  int* cursor  = (int*)walloc((size_t)N_NODES * 4);
  int* csr     = (int*)walloc((size_t)N_EDGES * 4);
  int* bsum    = (int*)walloc(4096);

  hipMemsetAsync(cnt, 0, (size_t)N_NODES * 4, stream);
  hipMemsetAsync(cursor, 0, (size_t)N_NODES * 4, stream);

  // weight prepack
  const int NW = (T_LAYERS - 1) * HID * HID;
  conv_k<<<(NW + 255) / 256, 256, 0, stream>>>(W_l, WlB, NW);
  conv_k<<<(NW + 255) / 256, 256, 0, stream>>>(W_r, WrB, NW);
  conv_k<<<(HID * HID + 255) / 256, 256, 0, stream>>>(Wp0, Wp0B, HID * HID);
  conv_k<<<(HID * HID + 255) / 256, 256, 0, stream>>>(Wp1, Wp1B, HID * HID);
  packw0_k<<<(HID * 64 + 255) / 256, 256, 0, stream>>>(W_l0, W_r0, W2);

  // CSR build
  count_k<<<(N_EDGES + 255) / 256, 256, 0, stream>>>(dst, cnt, N_EDGES);
  int P = (N_NODES + 1 + 1023) / 1024;
  scan_partial_k<<<P, 1024, 0, stream>>>(cnt, bsum, N_NODES);
  scan_small_k<<<1, 1024, 0, stream>>>(bsum, P);
  scan_final_k<<<P, 1024, 0, stream>>>(cnt, bsum, row_off, N_NODES);
  fill_k<<<(N_EDGES + 255) / 256, 256, 0, stream>>>(src, dst, row_off, cursor, csr, N_EDGES);

  const int GB = (N_NODES + 63) / 64;  // 1563 row-blocks

  // layer 0: agg10 -> pack -> MFMA GEMM (K=64: [x|agg10|pad] x [Wr0|Wl0|pad])
  agg10_k<<<(N_NODES + 7) / 8, 256, 0, stream>>>(x, row_off, csr, agg10, N_NODES);
  pack0_k<<<(N_NODES * 64 + 255) / 256, 256, 0, stream>>>(x, agg10, X2, N_NODES);
  mfma_gemm_k<64, false, 0, false><<<GB, 512, 0, stream>>>(
      X2, W2, nullptr, nullptr, b_l0, bn_g, bn_b, bn_m, bn_v, h,
      nullptr, nullptr, nullptr);

  // layers 1..4 (dual MFMA GEMM, in-place h update)
  for (int t = 1; t < T_LAYERS; ++t) {
    aggv_k<<<(N_NODES + 3) / 4, 256, 0, stream>>>(h, row_off, csr, agg, N_NODES);
    mfma_gemm_k<HID, true, 0, false><<<GB, 512, 0, stream>>>(
        agg, WlB + (size_t)(t - 1) * HID * HID,
        h,   WrB + (size_t)(t - 1) * HID * HID,
        b_l + (size_t)(t - 1) * HID,
        bn_g + (size_t)t * HID, bn_b + (size_t)t * HID,
        bn_m + (size_t)t * HID, bn_v + (size_t)t * HID,
        h, nullptr, nullptr, nullptr);
  }

  // projection MLP: proj0 in-place on h; proj1 fused with the 384->3 output
  mfma_gemm_k<HID, false, 1, false><<<GB, 512, 0, stream>>>(
      h, Wp0B, nullptr, nullptr, bp0, pbn_g, pbn_b, pbn_m, pbn_v, h,
      nullptr, nullptr, nullptr);
  mfma_gemm_k<HID, false, 1, true><<<GB, 512, 0, stream>>>(
      h, Wp1B, nullptr, nullptr, bp1, pbn_g + HID, pbn_b + HID, pbn_m + HID, pbn_v + HID, h,
      Wp2, bp2, (float*)d_out);
}